// Round 16
// baseline (37.909 us; speedup 1.0000x reference)
//
#include <hip/hip_runtime.h>
#include <math.h>

#define NPTS   8192
#define BITS   64
#define NCLS   101
#define TILE   128
#define NT     (NPTS / TILE)            // 64 i-tiles
#define NSTR   32                       // j-strips of 256 cols
#define NBLK   1056                     // valid (ti, strip) blocks
#define WS_CLS (3 * NBLK)
#define SCALE  0.84932184f              // sqrt(0.5*log2 e): acc = t = theta*log2(e)
#define LN2    0.6931471805599453
#define SCH_BITS 1064872494             // (127<<23) - 0.0573*2^23 (mean-zero Schraudolph)

// ws doubles: [0,NBLK) sp_all | [N,2N) sp_same | [2N,3N) t_same | [3N,4N) cls

typedef short    bf16x8   __attribute__((ext_vector_type(8)));
typedef unsigned short ushort8v __attribute__((ext_vector_type(8)));
typedef float    f32x16  __attribute__((ext_vector_type(16)));
typedef float    f32x2   __attribute__((ext_vector_type(2)));

__device__ __forceinline__ float flog2(float x) {
    float r; asm("v_log_f32 %0, %1" : "=v"(r) : "v"(x)); return r;
}
__device__ __forceinline__ unsigned cvt_pk_bf16(float lo, float hi) {
    unsigned r;
    asm("v_cvt_pk_bf16_f32 %0, %1, %2" : "=v"(r) : "v"(lo), "v"(hi));
    return r;
}

// ---------------------------------------------------------------------------
// Fused kernel: one 128x256 strip (two j-tiles sharing the A panel) + 8 cls
// rows per block. Epilogue: packed Schraudolph log-of-product (R15).
// ---------------------------------------------------------------------------
__global__ __launch_bounds__(256, 3) void hash_cls_kernel(const float* __restrict__ H,
                                                          const float* __restrict__ X,
                                                          const int* __restrict__ tgt,
                                                          double* __restrict__ ws) {
    __shared__ unsigned short As[TILE * BITS];        // 16 KiB
    __shared__ unsigned short Bs[2 * TILE * BITS];    // 32 KiB
    __shared__ int tI[TILE];
    __shared__ int tJ[2 * TILE];
    __shared__ float red[16];

    const int tid = threadIdx.x;
    const int p = blockIdx.x;

    // p -> (ti, s): per-ti strip count = 32 - (ti>>1)
    int ti = 0, off = 0;
    while (off + (NSTR - (ti >> 1)) <= p) { off += NSTR - (ti >> 1); ++ti; }
    const int s = (ti >> 1) + (p - off);
    const int i0 = ti * TILE;
    const int j0 = s * 256;
    const int lane = tid & 63, wave = tid >> 6;

    if (tid < TILE) tI[tid] = tgt[i0 + tid];
    tJ[tid] = tgt[j0 + tid];

    // ---- staging phase 1: issue ALL 24 float4-pair loads (A:128 + B:256 rows) ----
    float4 buf0[12], buf1[12];
#pragma unroll
    for (int it = 0; it < 12; ++it) {
        const int idx = tid + it * 256;      // 3072 chunks of 8 elems
        const int row = idx >> 3;            // 0..383
        const int c   = idx & 7;
        const int grow = (row < TILE) ? (i0 + row) : (j0 + row - TILE);
        const float* src = H + (size_t)grow * BITS + c * 8;
        buf0[it] = *(const float4*)src;
        buf1[it] = *(const float4*)(src + 4);
    }

    // ---- cls loads hoisted (2 rows per wave) ----
    const int crow0 = p * 8 + wave * 2;
    float cx1[2], cx2[2], cxt[2];
#pragma unroll
    for (int rr = 0; rr < 2; ++rr) {
        const int crow = crow0 + rr;
        cx1[rr] = -INFINITY; cx2[rr] = -INFINITY; cxt[rr] = 0.f;
        if (crow < NPTS) {
            const float* x = X + (size_t)crow * NCLS;
            cx1[rr] = x[lane];
            cx2[rr] = (lane + 64 < NCLS) ? x[lane + 64] : -INFINITY;
            cxt[rr] = x[tgt[crow]];
        }
    }

    // ---- staging phase 2: packed convert + swizzled LDS write ----
#pragma unroll
    for (int it = 0; it < 12; ++it) {
        const int idx = tid + it * 256;
        const int row = idx >> 3;
        const int c   = idx & 7;
        uint4 v;
        v.x = cvt_pk_bf16(buf0[it].x * SCALE, buf0[it].y * SCALE);
        v.y = cvt_pk_bf16(buf0[it].z * SCALE, buf0[it].w * SCALE);
        v.z = cvt_pk_bf16(buf1[it].x * SCALE, buf1[it].y * SCALE);
        v.w = cvt_pk_bf16(buf1[it].z * SCALE, buf1[it].w * SCALE);
        if (row < TILE) {
            *(uint4*)&As[row * BITS + ((c ^ (row & 7)) * 8)] = v;
        } else {
            const int rb = row - TILE;
            *(uint4*)&Bs[rb * BITS + ((c ^ (rb & 7)) * 8)] = v;
        }
    }
    __syncthreads();

    const int wr = wave >> 1, wc = wave & 1;
    const int lrow = lane & 31, hi = lane >> 5;

    auto ldfrag = [](const unsigned short* S, int row, int chunk) -> bf16x8 {
        ushort8v r = *(const ushort8v*)&S[row * BITS + ((chunk ^ (row & 7)) * 8)];
        return __builtin_bit_cast(bf16x8, r);
    };

    // A-fragments loaded ONCE, reused for both sub-tiles
    bf16x8 a0[4], a1[4];
#pragma unroll
    for (int ks = 0; ks < 4; ++ks) {
        const int ch = ks * 2 + hi;
        a0[ks] = ldfrag(As, wr * 64 +      lrow, ch);
        a1[ks] = ldfrag(As, wr * 64 + 32 + lrow, ch);
    }

    float s_all = 0.f, s_same = 0.f, t_same = 0.f;

#pragma unroll
    for (int st = 0; st < 2; ++st) {
        const int tjst = 2 * s + st;
        if (tjst < ti) continue;                       // below diagonal
        const bool diag = (tjst == ti);
        const unsigned short* Bsub = Bs + st * TILE * BITS;

        f32x16 c00, c01, c10, c11;
#pragma unroll
        for (int e = 0; e < 16; ++e) { c00[e] = 0.f; c01[e] = 0.f; c10[e] = 0.f; c11[e] = 0.f; }

#pragma unroll
        for (int ks = 0; ks < 4; ++ks) {
            const int ch = ks * 2 + hi;
            bf16x8 b0 = ldfrag(Bsub, wc * 64 +      lrow, ch);
            bf16x8 b1 = ldfrag(Bsub, wc * 64 + 32 + lrow, ch);
            c00 = __builtin_amdgcn_mfma_f32_32x32x16_bf16(a0[ks], b0, c00, 0, 0, 0);
            c01 = __builtin_amdgcn_mfma_f32_32x32x16_bf16(a0[ks], b1, c01, 0, 0, 0);
            c10 = __builtin_amdgcn_mfma_f32_32x32x16_bf16(a1[ks], b0, c10, 0, 0, 0);
            c11 = __builtin_amdgcn_mfma_f32_32x32x16_bf16(a1[ks], b1, c11, 0, 0, 0);
        }

        f32x2 prodA = {1.f, 1.f}, prodS = {1.f, 1.f};
        f32x2 sRelu = {0.f, 0.f}, sReluS = {0.f, 0.f}, tSum = {0.f, 0.f};

        if (!diag) {
#pragma unroll
            for (int it = 0; it < 2; ++it) {
                int trow[16];
#pragma unroll
                for (int r = 0; r < 16; ++r)
                    trow[r] = tI[wr * 64 + it * 32 + (r & 3) + 8 * (r >> 2) + 4 * hi];
#pragma unroll
                for (int jt = 0; jt < 2; ++jt) {
                    const int tc = tJ[st * TILE + wc * 64 + jt * 32 + lrow];
                    const f32x16& C = it ? (jt ? c11 : c10) : (jt ? c01 : c00);
#pragma unroll
                    for (int r = 0; r < 16; r += 2) {
                        float t0 = C[r], t1 = C[r + 1];
                        float n0 = __uint_as_float(__float_as_uint(t0) | 0x80000000u);
                        float n1 = __uint_as_float(__float_as_uint(t1) | 0x80000000u);
                        float u0 = __int_as_float((int)(n0 * 8388608.0f) + SCH_BITS);
                        float u1 = __int_as_float((int)(n1 * 8388608.0f) + SCH_BITS);
                        bool  m0 = (trow[r] == tc), m1 = (trow[r + 1] == tc);
                        f32x2 u2;  u2[0] = u0;            u2[1] = u1;
                        f32x2 um;  um[0] = m0 ? u0 : 0.f; um[1] = m1 ? u1 : 0.f;
                        prodA = prodA + prodA * u2;
                        prodS = prodS + prodS * um;
                        f32x2 rl;  rl[0] = fmaxf(t0, 0.f); rl[1] = fmaxf(t1, 0.f);
                        sRelu = sRelu + rl;
                        f32x2 rm;  rm[0] = m0 ? rl[0] : 0.f; rm[1] = m1 ? rl[1] : 0.f;
                        sReluS = sReluS + rm;
                        f32x2 tm;  tm[0] = m0 ? t0 : 0.f; tm[1] = m1 ? t1 : 0.f;
                        tSum = tSum + tm;
                    }
                }
            }
        } else {
#pragma unroll
            for (int it = 0; it < 2; ++it) {
                int trow[16], lrr[16];
#pragma unroll
                for (int r = 0; r < 16; ++r) {
                    lrr[r] = wr * 64 + it * 32 + (r & 3) + 8 * (r >> 2) + 4 * hi;
                    trow[r] = tI[lrr[r]];
                }
#pragma unroll
                for (int jt = 0; jt < 2; ++jt) {
                    const int lc = wc * 64 + jt * 32 + lrow;
                    const int tc = tJ[st * TILE + lc];
                    const f32x16& C = it ? (jt ? c11 : c10) : (jt ? c01 : c00);
#pragma unroll
                    for (int r = 0; r < 16; r += 2) {
                        float t0 = C[r], t1 = C[r + 1];
                        float n0 = __uint_as_float(__float_as_uint(t0) | 0x80000000u);
                        float n1 = __uint_as_float(__float_as_uint(t1) | 0x80000000u);
                        float u0 = __int_as_float((int)(n0 * 8388608.0f) + SCH_BITS);
                        float u1 = __int_as_float((int)(n1 * 8388608.0f) + SCH_BITS);
                        bool  v0 = lc > lrr[r],          v1 = lc > lrr[r + 1];
                        bool  m0 = v0 && (trow[r] == tc), m1 = v1 && (trow[r + 1] == tc);
                        f32x2 uv;  uv[0] = v0 ? u0 : 0.f; uv[1] = v1 ? u1 : 0.f;
                        f32x2 um;  um[0] = m0 ? u0 : 0.f; um[1] = m1 ? u1 : 0.f;
                        prodA = prodA + prodA * uv;
                        prodS = prodS + prodS * um;
                        f32x2 rl;  rl[0] = fmaxf(t0, 0.f); rl[1] = fmaxf(t1, 0.f);
                        f32x2 rv;  rv[0] = v0 ? rl[0] : 0.f; rv[1] = v1 ? rl[1] : 0.f;
                        sRelu = sRelu + rv;
                        f32x2 rm;  rm[0] = m0 ? rl[0] : 0.f; rm[1] = m1 ? rl[1] : 0.f;
                        sReluS = sReluS + rm;
                        f32x2 tm;  tm[0] = m0 ? t0 : 0.f; tm[1] = m1 ? t1 : 0.f;
                        tSum = tSum + tm;
                    }
                }
            }
        }

        s_all  += (sRelu[0]  + sRelu[1])  + flog2(prodA[0] * prodA[1]);
        s_same += (sReluS[0] + sReluS[1]) + flog2(prodS[0] * prodS[1]);
        t_same += tSum[0] + tSum[1];
    }

#pragma unroll
    for (int d = 32; d > 0; d >>= 1) {
        s_all  += __shfl_xor(s_all,  d, 64);
        s_same += __shfl_xor(s_same, d, 64);
        t_same += __shfl_xor(t_same, d, 64);
    }
    if (lane == 0) { red[wave] = s_all; red[4 + wave] = s_same; red[8 + wave] = t_same; }

    {   // cls softmax on preloaded registers (2 rows per wave)
        float nll = 0.f;
#pragma unroll
        for (int rr = 0; rr < 2; ++rr) {
            if (crow0 + rr < NPTS) {
                float m = fmaxf(cx1[rr], cx2[rr]);
#pragma unroll
                for (int d = 32; d > 0; d >>= 1) m = fmaxf(m, __shfl_xor(m, d, 64));
                float e = __expf(cx1[rr] - m)
                        + ((lane + 64 < NCLS) ? __expf(cx2[rr] - m) : 0.f);
#pragma unroll
                for (int d = 32; d > 0; d >>= 1) e += __shfl_xor(e, d, 64);
                if (lane == 0) nll += m + __logf(e) - cxt[rr];
            }
        }
        if (lane == 0) red[12 + wave] = nll;
    }
    __syncthreads();
    if (tid == 0) {
        ws[p]            = (double)red[0]  + (double)red[1]  + (double)red[2]  + (double)red[3];
        ws[NBLK + p]     = (double)red[4]  + (double)red[5]  + (double)red[6]  + (double)red[7];
        ws[2 * NBLK + p] = (double)red[8]  + (double)red[9]  + (double)red[10] + (double)red[11];
        ws[WS_CLS + p]   = (double)red[12] + (double)red[13] + (double)red[14] + (double)red[15];
    }
}

// ---------------------------------------------------------------------------
// Finalize (1024 threads): histogram -> S0/S1; double reduction; ln2 fold.
// ---------------------------------------------------------------------------
__global__ __launch_bounds__(1024) void final_kernel(const int* __restrict__ tgt,
                                                     const double* __restrict__ ws,
                                                     float* __restrict__ out) {
    __shared__ int hist[NCLS];
    __shared__ double r0[1024], r1[1024], r2[1024], rc[1024];
    const int tid = threadIdx.x;

    if (tid < NCLS) hist[tid] = 0;
    __syncthreads();
    for (int i = tid; i < NPTS; i += 1024) atomicAdd(&hist[tgt[i]], 1);
    __syncthreads();

    double a = 0.0, s = 0.0, t = 0.0, c = 0.0;
    for (int i = tid; i < NBLK; i += 1024) {
        a += ws[i];
        s += ws[NBLK + i];
        t += ws[2 * NBLK + i];
        c += ws[WS_CLS + i];
    }
    r0[tid] = a; r1[tid] = s; r2[tid] = t; rc[tid] = c;
    __syncthreads();
    for (int sd = 512; sd > 0; sd >>= 1) {
        if (tid < sd) {
            r0[tid] += r0[tid + sd];
            r1[tid] += r1[tid + sd];
            r2[tid] += r2[tid + sd];
            rc[tid] += rc[tid + sd];
        }
        __syncthreads();
    }

    if (tid == 0) {
        double n_pos = 0.0;
        for (int k = 0; k < NCLS; k++) {
            double cc = (double)hist[k];
            n_pos += cc * cc;
        }
        const double Nd = (double)NPTS;
        double S1 = n_pos - Nd;
        double S0 = Nd * Nd - n_pos;
        if (S0 == 0.0) S0 = 1.0;
        if (S1 == 0.0) S1 = 1.0;
        const double S = S0 + S1;
        const double sum_lower =
            ((S / S0) * (r0[0] - r1[0]) + (S / S1) * (r1[0] - r2[0])) * LN2;
        const double count = Nd * (Nd - 1.0) * 0.5;
        const double hash_loss = sum_lower / count;
        const double cls_loss  = rc[0] / Nd;
        const double loss = 1.0 * cls_loss + 0.01 * hash_loss;
        out[0] = (float)hash_loss;
        out[1] = (float)cls_loss;
        out[2] = (float)loss;
    }
}

// ---------------------------------------------------------------------------
extern "C" void kernel_launch(void* const* d_in, const int* in_sizes, int n_in,
                              void* d_out, int out_size, void* d_ws, size_t ws_size,
                              hipStream_t stream) {
    const float* H   = (const float*)d_in[0];
    const float* X   = (const float*)d_in[1];
    const int*   tgt = (const int*)d_in[2];
    float* out = (float*)d_out;
    double* wsd = (double*)d_ws;

    hash_cls_kernel<<<NBLK, 256, 0, stream>>>(H, X, tgt, wsd);
    final_kernel<<<1, 1024, 0, stream>>>(tgt, wsd, out);
}

// Round 17
// 37.077 us; speedup vs baseline: 1.0224x; 1.0224x over previous
//
#include <hip/hip_runtime.h>
#include <math.h>

#define NPTS   8192
#define BITS   64
#define NCLS   101
#define TILE   128
#define NT     (NPTS / TILE)            // 64 i-tiles
#define NSTR   32                       // j-strips of 256 cols
#define NBLK   1056                     // valid (ti, strip) blocks
#define WS_CLS (3 * NBLK)
#define SCALE  0.84932184f              // sqrt(0.5*log2 e): acc = t = theta*log2(e)
#define LN2    0.6931471805599453
#define SCH_BITS 1064872494             // (127<<23) - 0.0573*2^23 (mean-zero Schraudolph)

// ws doubles: [0,NBLK) sp_all | [N,2N) sp_same | [2N,3N) t_same | [3N,4N) cls

typedef short    bf16x8   __attribute__((ext_vector_type(8)));
typedef unsigned short ushort8v __attribute__((ext_vector_type(8)));
typedef float    f32x16  __attribute__((ext_vector_type(16)));
typedef float    f32x2   __attribute__((ext_vector_type(2)));

__device__ __forceinline__ float flog2(float x) {
    float r; asm("v_log_f32 %0, %1" : "=v"(r) : "v"(x)); return r;
}
__device__ __forceinline__ unsigned cvt_pk_bf16(float lo, float hi) {
    unsigned r;
    asm("v_cvt_pk_bf16_f32 %0, %1, %2" : "=v"(r) : "v"(lo), "v"(hi));
    return r;
}

// ---------------------------------------------------------------------------
// Fused kernel: one 128x256 strip (two j-tiles sharing the A panel) + 8 cls
// rows per block. Staging in TWO spill-free batches (<=8 float4-pairs live).
// ---------------------------------------------------------------------------
__global__ __launch_bounds__(256, 3) void hash_cls_kernel(const float* __restrict__ H,
                                                          const float* __restrict__ X,
                                                          const int* __restrict__ tgt,
                                                          double* __restrict__ ws) {
    __shared__ unsigned short As[TILE * BITS];        // 16 KiB
    __shared__ unsigned short Bs[2 * TILE * BITS];    // 32 KiB
    __shared__ int tI[TILE];
    __shared__ int tJ[2 * TILE];
    __shared__ float red[16];

    const int tid = threadIdx.x;
    const int p = blockIdx.x;

    // p -> (ti, s): per-ti strip count = 32 - (ti>>1)
    int ti = 0, off = 0;
    while (off + (NSTR - (ti >> 1)) <= p) { off += NSTR - (ti >> 1); ++ti; }
    const int s = (ti >> 1) + (p - off);
    const int i0 = ti * TILE;
    const int j0 = s * 256;
    const int lane = tid & 63, wave = tid >> 6;

    if (tid < TILE) tI[tid] = tgt[i0 + tid];
    tJ[tid] = tgt[j0 + tid];

    // ---- cls loads hoisted (2 rows per wave) ----
    const int crow0 = p * 8 + wave * 2;
    float cx1[2], cx2[2], cxt[2];
#pragma unroll
    for (int rr = 0; rr < 2; ++rr) {
        const int crow = crow0 + rr;
        cx1[rr] = -INFINITY; cx2[rr] = -INFINITY; cxt[rr] = 0.f;
        if (crow < NPTS) {
            const float* x = X + (size_t)crow * NCLS;
            cx1[rr] = x[lane];
            cx2[rr] = (lane + 64 < NCLS) ? x[lane + 64] : -INFINITY;
            cxt[rr] = x[tgt[crow]];
        }
    }

    // ---- staging: batch 1 = chunks it 0..7 (rows 0..255), batch 2 = it 8..11 ----
    float4 b0[8], b1[8];
#pragma unroll
    for (int it = 0; it < 8; ++it) {                 // issue 16 loads (64 VGPRs)
        const int idx = tid + it * 256;
        const int row = idx >> 3;
        const int c   = idx & 7;
        const int grow = (row < TILE) ? (i0 + row) : (j0 + row - TILE);
        const float* src = H + (size_t)grow * BITS + c * 8;
        b0[it] = *(const float4*)src;
        b1[it] = *(const float4*)(src + 4);
    }
#pragma unroll
    for (int it = 0; it < 8; ++it) {                 // convert + swizzled write
        const int idx = tid + it * 256;
        const int row = idx >> 3;
        const int c   = idx & 7;
        uint4 v;
        v.x = cvt_pk_bf16(b0[it].x * SCALE, b0[it].y * SCALE);
        v.y = cvt_pk_bf16(b0[it].z * SCALE, b0[it].w * SCALE);
        v.z = cvt_pk_bf16(b1[it].x * SCALE, b1[it].y * SCALE);
        v.w = cvt_pk_bf16(b1[it].z * SCALE, b1[it].w * SCALE);
        if (row < TILE) {
            *(uint4*)&As[row * BITS + ((c ^ (row & 7)) * 8)] = v;
        } else {
            const int rb = row - TILE;
            *(uint4*)&Bs[rb * BITS + ((c ^ (rb & 7)) * 8)] = v;
        }
    }
#pragma unroll
    for (int it = 0; it < 4; ++it) {                 // batch 2: issue 8 loads (reuse buf)
        const int idx = tid + (it + 8) * 256;
        const int row = idx >> 3;                    // 256..383 -> B rows 128..255
        const int c   = idx & 7;
        const float* src = H + (size_t)(j0 + row - TILE) * BITS + c * 8;
        b0[it] = *(const float4*)src;
        b1[it] = *(const float4*)(src + 4);
    }
#pragma unroll
    for (int it = 0; it < 4; ++it) {
        const int idx = tid + (it + 8) * 256;
        const int rb  = (idx >> 3) - TILE;
        const int c   = idx & 7;
        uint4 v;
        v.x = cvt_pk_bf16(b0[it].x * SCALE, b0[it].y * SCALE);
        v.y = cvt_pk_bf16(b0[it].z * SCALE, b0[it].w * SCALE);
        v.z = cvt_pk_bf16(b1[it].x * SCALE, b1[it].y * SCALE);
        v.w = cvt_pk_bf16(b1[it].z * SCALE, b1[it].w * SCALE);
        *(uint4*)&Bs[rb * BITS + ((c ^ (rb & 7)) * 8)] = v;
    }
    __syncthreads();

    const int wr = wave >> 1, wc = wave & 1;
    const int lrow = lane & 31, hi = lane >> 5;

    auto ldfrag = [](const unsigned short* S, int row, int chunk) -> bf16x8 {
        ushort8v r = *(const ushort8v*)&S[row * BITS + ((chunk ^ (row & 7)) * 8)];
        return __builtin_bit_cast(bf16x8, r);
    };

    // A-fragments loaded ONCE, reused for both sub-tiles
    bf16x8 a0[4], a1[4];
#pragma unroll
    for (int ks = 0; ks < 4; ++ks) {
        const int ch = ks * 2 + hi;
        a0[ks] = ldfrag(As, wr * 64 +      lrow, ch);
        a1[ks] = ldfrag(As, wr * 64 + 32 + lrow, ch);
    }

    float s_all = 0.f, s_same = 0.f, t_same = 0.f;

#pragma unroll
    for (int st = 0; st < 2; ++st) {
        const int tjst = 2 * s + st;
        if (tjst < ti) continue;                       // below diagonal
        const bool diag = (tjst == ti);
        const unsigned short* Bsub = Bs + st * TILE * BITS;

        f32x16 c00, c01, c10, c11;
#pragma unroll
        for (int e = 0; e < 16; ++e) { c00[e] = 0.f; c01[e] = 0.f; c10[e] = 0.f; c11[e] = 0.f; }

#pragma unroll
        for (int ks = 0; ks < 4; ++ks) {
            const int ch = ks * 2 + hi;
            bf16x8 bb0 = ldfrag(Bsub, wc * 64 +      lrow, ch);
            bf16x8 bb1 = ldfrag(Bsub, wc * 64 + 32 + lrow, ch);
            c00 = __builtin_amdgcn_mfma_f32_32x32x16_bf16(a0[ks], bb0, c00, 0, 0, 0);
            c01 = __builtin_amdgcn_mfma_f32_32x32x16_bf16(a0[ks], bb1, c01, 0, 0, 0);
            c10 = __builtin_amdgcn_mfma_f32_32x32x16_bf16(a1[ks], bb0, c10, 0, 0, 0);
            c11 = __builtin_amdgcn_mfma_f32_32x32x16_bf16(a1[ks], bb1, c11, 0, 0, 0);
        }

        f32x2 prodA = {1.f, 1.f}, prodS = {1.f, 1.f};
        f32x2 sRelu = {0.f, 0.f}, sReluS = {0.f, 0.f}, tSum = {0.f, 0.f};

        if (!diag) {
#pragma unroll
            for (int it = 0; it < 2; ++it) {
                int trow[16];
#pragma unroll
                for (int r = 0; r < 16; ++r)
                    trow[r] = tI[wr * 64 + it * 32 + (r & 3) + 8 * (r >> 2) + 4 * hi];
#pragma unroll
                for (int jt = 0; jt < 2; ++jt) {
                    const int tc = tJ[st * TILE + wc * 64 + jt * 32 + lrow];
                    const f32x16& C = it ? (jt ? c11 : c10) : (jt ? c01 : c00);
#pragma unroll
                    for (int r = 0; r < 16; r += 2) {
                        float t0 = C[r], t1 = C[r + 1];
                        float n0 = __uint_as_float(__float_as_uint(t0) | 0x80000000u);
                        float n1 = __uint_as_float(__float_as_uint(t1) | 0x80000000u);
                        float u0 = __int_as_float((int)(n0 * 8388608.0f) + SCH_BITS);
                        float u1 = __int_as_float((int)(n1 * 8388608.0f) + SCH_BITS);
                        bool  m0 = (trow[r] == tc), m1 = (trow[r + 1] == tc);
                        f32x2 u2;  u2[0] = u0;            u2[1] = u1;
                        f32x2 um;  um[0] = m0 ? u0 : 0.f; um[1] = m1 ? u1 : 0.f;
                        prodA = prodA + prodA * u2;
                        prodS = prodS + prodS * um;
                        f32x2 rl;  rl[0] = fmaxf(t0, 0.f); rl[1] = fmaxf(t1, 0.f);
                        sRelu = sRelu + rl;
                        f32x2 rm;  rm[0] = m0 ? rl[0] : 0.f; rm[1] = m1 ? rl[1] : 0.f;
                        sReluS = sReluS + rm;
                        f32x2 tm;  tm[0] = m0 ? t0 : 0.f; tm[1] = m1 ? t1 : 0.f;
                        tSum = tSum + tm;
                    }
                }
            }
        } else {
#pragma unroll
            for (int it = 0; it < 2; ++it) {
                int trow[16], lrr[16];
#pragma unroll
                for (int r = 0; r < 16; ++r) {
                    lrr[r] = wr * 64 + it * 32 + (r & 3) + 8 * (r >> 2) + 4 * hi;
                    trow[r] = tI[lrr[r]];
                }
#pragma unroll
                for (int jt = 0; jt < 2; ++jt) {
                    const int lc = wc * 64 + jt * 32 + lrow;
                    const int tc = tJ[st * TILE + lc];
                    const f32x16& C = it ? (jt ? c11 : c10) : (jt ? c01 : c00);
#pragma unroll
                    for (int r = 0; r < 16; r += 2) {
                        float t0 = C[r], t1 = C[r + 1];
                        float n0 = __uint_as_float(__float_as_uint(t0) | 0x80000000u);
                        float n1 = __uint_as_float(__float_as_uint(t1) | 0x80000000u);
                        float u0 = __int_as_float((int)(n0 * 8388608.0f) + SCH_BITS);
                        float u1 = __int_as_float((int)(n1 * 8388608.0f) + SCH_BITS);
                        bool  v0 = lc > lrr[r],          v1 = lc > lrr[r + 1];
                        bool  m0 = v0 && (trow[r] == tc), m1 = v1 && (trow[r + 1] == tc);
                        f32x2 uv;  uv[0] = v0 ? u0 : 0.f; uv[1] = v1 ? u1 : 0.f;
                        f32x2 um;  um[0] = m0 ? u0 : 0.f; um[1] = m1 ? u1 : 0.f;
                        prodA = prodA + prodA * uv;
                        prodS = prodS + prodS * um;
                        f32x2 rl;  rl[0] = fmaxf(t0, 0.f); rl[1] = fmaxf(t1, 0.f);
                        f32x2 rv;  rv[0] = v0 ? rl[0] : 0.f; rv[1] = v1 ? rl[1] : 0.f;
                        sRelu = sRelu + rv;
                        f32x2 rm;  rm[0] = m0 ? rl[0] : 0.f; rm[1] = m1 ? rl[1] : 0.f;
                        sReluS = sReluS + rm;
                        f32x2 tm;  tm[0] = m0 ? t0 : 0.f; tm[1] = m1 ? t1 : 0.f;
                        tSum = tSum + tm;
                    }
                }
            }
        }

        s_all  += (sRelu[0]  + sRelu[1])  + flog2(prodA[0] * prodA[1]);
        s_same += (sReluS[0] + sReluS[1]) + flog2(prodS[0] * prodS[1]);
        t_same += tSum[0] + tSum[1];
    }

#pragma unroll
    for (int d = 32; d > 0; d >>= 1) {
        s_all  += __shfl_xor(s_all,  d, 64);
        s_same += __shfl_xor(s_same, d, 64);
        t_same += __shfl_xor(t_same, d, 64);
    }
    if (lane == 0) { red[wave] = s_all; red[4 + wave] = s_same; red[8 + wave] = t_same; }

    {   // cls softmax on preloaded registers (2 rows per wave)
        float nll = 0.f;
#pragma unroll
        for (int rr = 0; rr < 2; ++rr) {
            if (crow0 + rr < NPTS) {
                float m = fmaxf(cx1[rr], cx2[rr]);
#pragma unroll
                for (int d = 32; d > 0; d >>= 1) m = fmaxf(m, __shfl_xor(m, d, 64));
                float e = __expf(cx1[rr] - m)
                        + ((lane + 64 < NCLS) ? __expf(cx2[rr] - m) : 0.f);
#pragma unroll
                for (int d = 32; d > 0; d >>= 1) e += __shfl_xor(e, d, 64);
                if (lane == 0) nll += m + __logf(e) - cxt[rr];
            }
        }
        if (lane == 0) red[12 + wave] = nll;
    }
    __syncthreads();
    if (tid == 0) {
        ws[p]            = (double)red[0]  + (double)red[1]  + (double)red[2]  + (double)red[3];
        ws[NBLK + p]     = (double)red[4]  + (double)red[5]  + (double)red[6]  + (double)red[7];
        ws[2 * NBLK + p] = (double)red[8]  + (double)red[9]  + (double)red[10] + (double)red[11];
        ws[WS_CLS + p]   = (double)red[12] + (double)red[13] + (double)red[14] + (double)red[15];
    }
}

// ---------------------------------------------------------------------------
// Finalize (1024 threads): histogram -> S0/S1; double reduction; ln2 fold.
// ---------------------------------------------------------------------------
__global__ __launch_bounds__(1024) void final_kernel(const int* __restrict__ tgt,
                                                     const double* __restrict__ ws,
                                                     float* __restrict__ out) {
    __shared__ int hist[NCLS];
    __shared__ double r0[1024], r1[1024], r2[1024], rc[1024];
    const int tid = threadIdx.x;

    if (tid < NCLS) hist[tid] = 0;
    __syncthreads();
    for (int i = tid; i < NPTS; i += 1024) atomicAdd(&hist[tgt[i]], 1);
    __syncthreads();

    double a = 0.0, s = 0.0, t = 0.0, c = 0.0;
    for (int i = tid; i < NBLK; i += 1024) {
        a += ws[i];
        s += ws[NBLK + i];
        t += ws[2 * NBLK + i];
        c += ws[WS_CLS + i];
    }
    r0[tid] = a; r1[tid] = s; r2[tid] = t; rc[tid] = c;
    __syncthreads();
    for (int sd = 512; sd > 0; sd >>= 1) {
        if (tid < sd) {
            r0[tid] += r0[tid + sd];
            r1[tid] += r1[tid + sd];
            r2[tid] += r2[tid + sd];
            rc[tid] += rc[tid + sd];
        }
        __syncthreads();
    }

    if (tid == 0) {
        double n_pos = 0.0;
        for (int k = 0; k < NCLS; k++) {
            double cc = (double)hist[k];
            n_pos += cc * cc;
        }
        const double Nd = (double)NPTS;
        double S1 = n_pos - Nd;
        double S0 = Nd * Nd - n_pos;
        if (S0 == 0.0) S0 = 1.0;
        if (S1 == 0.0) S1 = 1.0;
        const double S = S0 + S1;
        const double sum_lower =
            ((S / S0) * (r0[0] - r1[0]) + (S / S1) * (r1[0] - r2[0])) * LN2;
        const double count = Nd * (Nd - 1.0) * 0.5;
        const double hash_loss = sum_lower / count;
        const double cls_loss  = rc[0] / Nd;
        const double loss = 1.0 * cls_loss + 0.01 * hash_loss;
        out[0] = (float)hash_loss;
        out[1] = (float)cls_loss;
        out[2] = (float)loss;
    }
}

// ---------------------------------------------------------------------------
extern "C" void kernel_launch(void* const* d_in, const int* in_sizes, int n_in,
                              void* d_out, int out_size, void* d_ws, size_t ws_size,
                              hipStream_t stream) {
    const float* H   = (const float*)d_in[0];
    const float* X   = (const float*)d_in[1];
    const int*   tgt = (const int*)d_in[2];
    float* out = (float*)d_out;
    double* wsd = (double*)d_ws;

    hash_cls_kernel<<<NBLK, 256, 0, stream>>>(H, X, tgt, wsd);
    final_kernel<<<1, 1024, 0, stream>>>(tgt, wsd, out);
}

// Round 18
// 32.618 us; speedup vs baseline: 1.1622x; 1.1367x over previous
//
#include <hip/hip_runtime.h>
#include <math.h>

#define NPTS   8192
#define BITS   64
#define NCLS   101
#define TILE   128
#define NT     (NPTS / TILE)            // 64
#define NPAIRS (NT * (NT + 1) / 2)      // 2080
#define WS_CLS (3 * NPAIRS)
#define SCALE  0.84932184f              // sqrt(0.5*log2 e): acc = t = theta*log2(e)
#define LN2    0.6931471805599453
#define SCH_BITS 1064872494             // (127<<23) - 0.0573*2^23 (mean-zero Schraudolph)

// ws doubles: [0,N) sp_all(log2 units) | [N,2N) sp_same | [2N,3N) t_same | [3N,4N) cls

typedef short    bf16x8   __attribute__((ext_vector_type(8)));
typedef unsigned short ushort8v __attribute__((ext_vector_type(8)));
typedef float    f32x16  __attribute__((ext_vector_type(16)));
typedef float    f32x2   __attribute__((ext_vector_type(2)));

__device__ __forceinline__ float flog2(float x) {
    float r; asm("v_log_f32 %0, %1" : "=v"(r) : "v"(x)); return r;
}
__device__ __forceinline__ unsigned cvt_pk_bf16(float lo, float hi) {
    unsigned r;
    asm("v_cvt_pk_bf16_f32 %0, %1, %2" : "=v"(r) : "v"(lo), "v"(hi));
    return r;
}
__device__ __forceinline__ void tile_map(int p, int& ti, int& tj) {
    float disc = (2.0f * NT + 1.0f) * (2.0f * NT + 1.0f) - 8.0f * (float)p;
    ti = (int)(((2.0f * NT + 1.0f) - sqrtf(disc)) * 0.5f);
    if (ti < 0) ti = 0;
    if (ti >= NT) ti = NT - 1;
    while (ti > 0 && (ti * NT - ti * (ti - 1) / 2) > p) ti--;
    while ((ti + 1) * NT - (ti + 1) * ti / 2 <= p) ti++;
    tj = ti + (p - (ti * NT - ti * (ti - 1) / 2));
}

// ---------------------------------------------------------------------------
// Fused hash tile + cls rows (R15 structure, 4-waves/SIMD occupancy).
// Epilogue: packed Schraudolph; masks as packed 0/1 -> one pk_fma per masked
// accumulator; relu-sum via (sum t - sum(-|t|)) / 2.
// ---------------------------------------------------------------------------
__global__ __launch_bounds__(256, 4) void hash_cls_kernel(const float* __restrict__ H,
                                                          const float* __restrict__ X,
                                                          const int* __restrict__ tgt,
                                                          double* __restrict__ ws) {
    __shared__ unsigned short As[TILE * BITS];
    __shared__ unsigned short Bs[TILE * BITS];
    __shared__ int tI[TILE];
    __shared__ int tJ[TILE];
    __shared__ float red[16];

    const int tid = threadIdx.x;
    const int p = blockIdx.x;
    int ti, tj; tile_map(p, ti, tj);
    const int i0 = ti * TILE, j0 = tj * TILE;
    const bool diag = (ti == tj);
    const int lane = tid & 63, wave = tid >> 6;

    if (tid < TILE) { tI[tid] = tgt[i0 + tid]; tJ[tid] = tgt[j0 + tid]; }

    // ---- staging phase 1: issue ALL 16 global float4 loads (deep MLP) ----
    float4 buf0[8], buf1[8];
#pragma unroll
    for (int it = 0; it < 8; ++it) {
        const int idx  = tid + it * 256;
        const int half = idx >> 10;
        const int lid  = idx & 1023;
        const int row  = lid >> 3;
        const int c    = lid & 7;
        const float* src = H + (size_t)((half ? j0 : i0) + row) * BITS + c * 8;
        buf0[it] = *(const float4*)src;
        buf1[it] = *(const float4*)(src + 4);
    }

    // ---- cls loads hoisted ----
    const int crow = p * 4 + wave;
    float cx1 = -INFINITY, cx2 = -INFINITY, cxt = 0.f;
    if (crow < NPTS) {
        const float* x = X + (size_t)crow * NCLS;
        cx1 = x[lane];
        cx2 = (lane + 64 < NCLS) ? x[lane + 64] : -INFINITY;
        cxt = x[tgt[crow]];
    }

    // ---- staging phase 2: packed convert + swizzled LDS write ----
#pragma unroll
    for (int it = 0; it < 8; ++it) {
        const int idx  = tid + it * 256;
        const int half = idx >> 10;
        const int lid  = idx & 1023;
        const int row  = lid >> 3;
        const int c    = lid & 7;
        uint4 v;
        v.x = cvt_pk_bf16(buf0[it].x * SCALE, buf0[it].y * SCALE);
        v.y = cvt_pk_bf16(buf0[it].z * SCALE, buf0[it].w * SCALE);
        v.z = cvt_pk_bf16(buf1[it].x * SCALE, buf1[it].y * SCALE);
        v.w = cvt_pk_bf16(buf1[it].z * SCALE, buf1[it].w * SCALE);
        unsigned short* dst = half ? Bs : As;
        *(uint4*)&dst[row * BITS + ((c ^ (row & 7)) * 8)] = v;
    }
    __syncthreads();

    const int wr = wave >> 1, wc = wave & 1;
    const int lrow = lane & 31, hi = lane >> 5;

    f32x16 c00, c01, c10, c11;
#pragma unroll
    for (int e = 0; e < 16; ++e) { c00[e] = 0.f; c01[e] = 0.f; c10[e] = 0.f; c11[e] = 0.f; }

    auto ldfrag = [](const unsigned short* S, int row, int chunk) -> bf16x8 {
        ushort8v r = *(const ushort8v*)&S[row * BITS + ((chunk ^ (row & 7)) * 8)];
        return __builtin_bit_cast(bf16x8, r);
    };

#pragma unroll
    for (int ks = 0; ks < 4; ++ks) {
        const int ch = ks * 2 + hi;
        bf16x8 a0 = ldfrag(As, wr * 64 +      lrow, ch);
        bf16x8 a1 = ldfrag(As, wr * 64 + 32 + lrow, ch);
        bf16x8 b0 = ldfrag(Bs, wc * 64 +      lrow, ch);
        bf16x8 b1 = ldfrag(Bs, wc * 64 + 32 + lrow, ch);
        c00 = __builtin_amdgcn_mfma_f32_32x32x16_bf16(a0, b0, c00, 0, 0, 0);
        c01 = __builtin_amdgcn_mfma_f32_32x32x16_bf16(a0, b1, c01, 0, 0, 0);
        c10 = __builtin_amdgcn_mfma_f32_32x32x16_bf16(a1, b0, c10, 0, 0, 0);
        c11 = __builtin_amdgcn_mfma_f32_32x32x16_bf16(a1, b1, c11, 0, 0, 0);
    }

    // packed epilogue state: products + {sum t, sum(-|t|)} unmasked & masked
    f32x2 prodA = {1.f, 1.f}, prodS = {1.f, 1.f};
    f32x2 sT = {0.f, 0.f}, sN = {0.f, 0.f}, sTS = {0.f, 0.f}, sNS = {0.f, 0.f};

    if (!diag) {
#pragma unroll
        for (int it = 0; it < 2; ++it) {
            int trow[16];
#pragma unroll
            for (int r = 0; r < 16; ++r)
                trow[r] = tI[wr * 64 + it * 32 + (r & 3) + 8 * (r >> 2) + 4 * hi];
#pragma unroll
            for (int jt = 0; jt < 2; ++jt) {
                const int tc = tJ[wc * 64 + jt * 32 + lrow];
                const f32x16& C = it ? (jt ? c11 : c10) : (jt ? c01 : c00);
#pragma unroll
                for (int r = 0; r < 16; r += 2) {
                    float t0 = C[r], t1 = C[r + 1];
                    float n0 = __uint_as_float(__float_as_uint(t0) | 0x80000000u);
                    float n1 = __uint_as_float(__float_as_uint(t1) | 0x80000000u);
                    f32x2 t2; t2[0] = t0; t2[1] = t1;
                    f32x2 n2; n2[0] = n0; n2[1] = n1;
                    f32x2 sc = n2 * 8388608.0f;                    // pk_mul
                    f32x2 u2;
                    u2[0] = __int_as_float((int)sc[0] + SCH_BITS); // ~2^{-|t|}
                    u2[1] = __int_as_float((int)sc[1] + SCH_BITS);
                    f32x2 mf;
                    mf[0] = (trow[r]     == tc) ? 1.f : 0.f;
                    mf[1] = (trow[r + 1] == tc) ? 1.f : 0.f;
                    prodA = prodA + prodA * u2;
                    prodS = prodS + prodS * (mf * u2);
                    sT  = sT  + t2;
                    sN  = sN  + n2;
                    sTS = sTS + mf * t2;
                    sNS = sNS + mf * n2;
                }
            }
        }
    } else {
#pragma unroll
        for (int it = 0; it < 2; ++it) {
            int trow[16], lrr[16];
#pragma unroll
            for (int r = 0; r < 16; ++r) {
                lrr[r] = wr * 64 + it * 32 + (r & 3) + 8 * (r >> 2) + 4 * hi;
                trow[r] = tI[lrr[r]];
            }
#pragma unroll
            for (int jt = 0; jt < 2; ++jt) {
                const int lc = wc * 64 + jt * 32 + lrow;
                const int tc = tJ[lc];
                const f32x16& C = it ? (jt ? c11 : c10) : (jt ? c01 : c00);
#pragma unroll
                for (int r = 0; r < 16; r += 2) {
                    float t0 = C[r], t1 = C[r + 1];
                    float n0 = __uint_as_float(__float_as_uint(t0) | 0x80000000u);
                    float n1 = __uint_as_float(__float_as_uint(t1) | 0x80000000u);
                    f32x2 t2; t2[0] = t0; t2[1] = t1;
                    f32x2 n2; n2[0] = n0; n2[1] = n1;
                    f32x2 sc = n2 * 8388608.0f;
                    f32x2 u2;
                    u2[0] = __int_as_float((int)sc[0] + SCH_BITS);
                    u2[1] = __int_as_float((int)sc[1] + SCH_BITS);
                    bool v0 = lc > lrr[r], v1 = lc > lrr[r + 1];
                    f32x2 vf; vf[0] = v0 ? 1.f : 0.f; vf[1] = v1 ? 1.f : 0.f;
                    f32x2 mf;
                    mf[0] = (v0 && trow[r]     == tc) ? 1.f : 0.f;
                    mf[1] = (v1 && trow[r + 1] == tc) ? 1.f : 0.f;
                    prodA = prodA + prodA * (vf * u2);
                    prodS = prodS + prodS * (mf * u2);
                    sT  = sT  + vf * t2;
                    sN  = sN  + vf * n2;
                    sTS = sTS + mf * t2;
                    sNS = sNS + mf * n2;
                }
            }
        }
    }

    // relu-sum = (sum t - sum(-|t|)) / 2
    float s_all  = 0.5f * ((sT[0] + sT[1]) - (sN[0] + sN[1])) + flog2(prodA[0] * prodA[1]);
    float s_same = 0.5f * ((sTS[0] + sTS[1]) - (sNS[0] + sNS[1])) + flog2(prodS[0] * prodS[1]);
    float t_same = sTS[0] + sTS[1];

#pragma unroll
    for (int d = 32; d > 0; d >>= 1) {
        s_all  += __shfl_xor(s_all,  d, 64);
        s_same += __shfl_xor(s_same, d, 64);
        t_same += __shfl_xor(t_same, d, 64);
    }
    if (lane == 0) { red[wave] = s_all; red[4 + wave] = s_same; red[8 + wave] = t_same; }

    {   // cls softmax on preloaded registers
        float nll = 0.f;
        if (crow < NPTS) {
            float m = fmaxf(cx1, cx2);
#pragma unroll
            for (int d = 32; d > 0; d >>= 1) m = fmaxf(m, __shfl_xor(m, d, 64));
            float e = __expf(cx1 - m) + ((lane + 64 < NCLS) ? __expf(cx2 - m) : 0.f);
#pragma unroll
            for (int d = 32; d > 0; d >>= 1) e += __shfl_xor(e, d, 64);
            if (lane == 0) nll = m + __logf(e) - cxt;
        }
        if (lane == 0) red[12 + wave] = nll;
    }
    __syncthreads();
    if (tid == 0) {
        ws[p]              = (double)red[0]  + (double)red[1]  + (double)red[2]  + (double)red[3];
        ws[NPAIRS + p]     = (double)red[4]  + (double)red[5]  + (double)red[6]  + (double)red[7];
        ws[2 * NPAIRS + p] = (double)red[8]  + (double)red[9]  + (double)red[10] + (double)red[11];
        ws[WS_CLS + p]     = (double)red[12] + (double)red[13] + (double)red[14] + (double)red[15];
    }
}

// ---------------------------------------------------------------------------
// Finalize: histogram -> S0/S1 weights; double reduction; ln2 fold here.
// ---------------------------------------------------------------------------
__global__ __launch_bounds__(256) void final_kernel(const int* __restrict__ tgt,
                                                    const double* __restrict__ ws,
                                                    float* __restrict__ out) {
    __shared__ int hist[NCLS];
    __shared__ double r0[256], r1[256], r2[256], rc[256];
    const int tid = threadIdx.x;

    for (int i = tid; i < NCLS; i += 256) hist[i] = 0;
    __syncthreads();
    for (int i = tid; i < NPTS; i += 256) atomicAdd(&hist[tgt[i]], 1);
    __syncthreads();

    double a = 0.0, s = 0.0, t = 0.0, c = 0.0;
    for (int i = tid; i < NPAIRS; i += 256) {
        a += ws[i];
        s += ws[NPAIRS + i];
        t += ws[2 * NPAIRS + i];
        c += ws[WS_CLS + i];
    }
    r0[tid] = a; r1[tid] = s; r2[tid] = t; rc[tid] = c;
    __syncthreads();
    for (int sdt = 128; sdt > 0; sdt >>= 1) {
        if (tid < sdt) {
            r0[tid] += r0[tid + sdt];
            r1[tid] += r1[tid + sdt];
            r2[tid] += r2[tid + sdt];
            rc[tid] += rc[tid + sdt];
        }
        __syncthreads();
    }

    if (tid == 0) {
        double n_pos = 0.0;
        for (int k = 0; k < NCLS; k++) {
            double cc = (double)hist[k];
            n_pos += cc * cc;
        }
        const double Nd = (double)NPTS;
        double S1 = n_pos - Nd;
        double S0 = Nd * Nd - n_pos;
        if (S0 == 0.0) S0 = 1.0;
        if (S1 == 0.0) S1 = 1.0;
        const double S = S0 + S1;
        const double sum_lower =
            ((S / S0) * (r0[0] - r1[0]) + (S / S1) * (r1[0] - r2[0])) * LN2;
        const double count = Nd * (Nd - 1.0) * 0.5;
        const double hash_loss = sum_lower / count;
        const double cls_loss  = rc[0] / Nd;
        const double loss = 1.0 * cls_loss + 0.01 * hash_loss;
        out[0] = (float)hash_loss;
        out[1] = (float)cls_loss;
        out[2] = (float)loss;
    }
}

// ---------------------------------------------------------------------------
extern "C" void kernel_launch(void* const* d_in, const int* in_sizes, int n_in,
                              void* d_out, int out_size, void* d_ws, size_t ws_size,
                              hipStream_t stream) {
    const float* H   = (const float*)d_in[0];
    const float* X   = (const float*)d_in[1];
    const int*   tgt = (const int*)d_in[2];
    float* out = (float*)d_out;
    double* wsd = (double*)d_ws;

    hash_cls_kernel<<<NPAIRS, 256, 0, stream>>>(H, X, tgt, wsd);
    final_kernel<<<1, 256, 0, stream>>>(tgt, wsd, out);
}

// Round 19
// 32.226 us; speedup vs baseline: 1.1763x; 1.0121x over previous
//
#include <hip/hip_runtime.h>
#include <math.h>

#define NPTS   8192
#define BITS   64
#define NCLS   101
#define TILE   128
#define NT     (NPTS / TILE)            // 64
#define NPAIRS (NT * (NT + 1) / 2)      // 2080
#define WS_CLS (3 * NPAIRS)
#define SCALE  0.84932184f              // sqrt(0.5*log2 e): acc = t = theta*log2(e)
#define LN2    0.6931471805599453
#define SCH_BITS 1064872494             // (127<<23) - 0.0573*2^23 (mean-zero Schraudolph)

// ws doubles: [0,N) sp_all(log2 units) | [N,2N) sp_same | [2N,3N) t_same | [3N,4N) cls

typedef short    bf16x8   __attribute__((ext_vector_type(8)));
typedef unsigned short ushort8v __attribute__((ext_vector_type(8)));
typedef float    f32x16  __attribute__((ext_vector_type(16)));
typedef float    f32x2   __attribute__((ext_vector_type(2)));

__device__ __forceinline__ float flog2(float x) {
    float r; asm("v_log_f32 %0, %1" : "=v"(r) : "v"(x)); return r;
}
__device__ __forceinline__ float fexp2(float x) {        // trans pipe: 2^x
    float r; asm("v_exp_f32 %0, %1" : "=v"(r) : "v"(x)); return r;
}
__device__ __forceinline__ unsigned cvt_pk_bf16(float lo, float hi) {
    unsigned r;
    asm("v_cvt_pk_bf16_f32 %0, %1, %2" : "=v"(r) : "v"(lo), "v"(hi));
    return r;
}
__device__ __forceinline__ void tile_map(int p, int& ti, int& tj) {
    float disc = (2.0f * NT + 1.0f) * (2.0f * NT + 1.0f) - 8.0f * (float)p;
    ti = (int)(((2.0f * NT + 1.0f) - sqrtf(disc)) * 0.5f);
    if (ti < 0) ti = 0;
    if (ti >= NT) ti = NT - 1;
    while (ti > 0 && (ti * NT - ti * (ti - 1) / 2) > p) ti--;
    while ((ti + 1) * NT - (ti + 1) * ti / 2 <= p) ti++;
    tj = ti + (p - (ti * NT - ti * (ti - 1) / 2));
}

// ---------------------------------------------------------------------------
// Fused hash tile + cls rows. (256,4) occupancy; staging in 2 spill-free
// batches (4 float4-pairs live). Epilogue: half Schraudolph (VALU pipe),
// half raw v_exp_f32 (trans pipe) — balances both issue pipes.
// ---------------------------------------------------------------------------
__global__ __launch_bounds__(256, 4) void hash_cls_kernel(const float* __restrict__ H,
                                                          const float* __restrict__ X,
                                                          const int* __restrict__ tgt,
                                                          double* __restrict__ ws) {
    __shared__ unsigned short As[TILE * BITS];
    __shared__ unsigned short Bs[TILE * BITS];
    __shared__ int tI[TILE];
    __shared__ int tJ[TILE];
    __shared__ float red[16];

    const int tid = threadIdx.x;
    const int p = blockIdx.x;
    int ti, tj; tile_map(p, ti, tj);
    const int i0 = ti * TILE, j0 = tj * TILE;
    const bool diag = (ti == tj);
    const int lane = tid & 63, wave = tid >> 6;

    if (tid < TILE) { tI[tid] = tgt[i0 + tid]; tJ[tid] = tgt[j0 + tid]; }

    // ---- cls loads hoisted ----
    const int crow = p * 4 + wave;
    float cx1 = -INFINITY, cx2 = -INFINITY, cxt = 0.f;
    if (crow < NPTS) {
        const float* x = X + (size_t)crow * NCLS;
        cx1 = x[lane];
        cx2 = (lane + 64 < NCLS) ? x[lane + 64] : -INFINITY;
        cxt = x[tgt[crow]];
    }

    // ---- staging: 2 batches of 4 float4-pairs (32 VGPRs in flight, no spill) ----
#pragma unroll
    for (int bb = 0; bb < 2; ++bb) {
        float4 buf0[4], buf1[4];
#pragma unroll
        for (int it = 0; it < 4; ++it) {
            const int idx  = tid + (bb * 4 + it) * 256;
            const int half = idx >> 10;
            const int lid  = idx & 1023;
            const int row  = lid >> 3;
            const int c    = lid & 7;
            const float* src = H + (size_t)((half ? j0 : i0) + row) * BITS + c * 8;
            buf0[it] = *(const float4*)src;
            buf1[it] = *(const float4*)(src + 4);
        }
#pragma unroll
        for (int it = 0; it < 4; ++it) {
            const int idx  = tid + (bb * 4 + it) * 256;
            const int half = idx >> 10;
            const int lid  = idx & 1023;
            const int row  = lid >> 3;
            const int c    = lid & 7;
            uint4 v;
            v.x = cvt_pk_bf16(buf0[it].x * SCALE, buf0[it].y * SCALE);
            v.y = cvt_pk_bf16(buf0[it].z * SCALE, buf0[it].w * SCALE);
            v.z = cvt_pk_bf16(buf1[it].x * SCALE, buf1[it].y * SCALE);
            v.w = cvt_pk_bf16(buf1[it].z * SCALE, buf1[it].w * SCALE);
            unsigned short* dst = half ? Bs : As;
            *(uint4*)&dst[row * BITS + ((c ^ (row & 7)) * 8)] = v;
        }
    }
    __syncthreads();

    const int wr = wave >> 1, wc = wave & 1;
    const int lrow = lane & 31, hi = lane >> 5;

    f32x16 c00, c01, c10, c11;
#pragma unroll
    for (int e = 0; e < 16; ++e) { c00[e] = 0.f; c01[e] = 0.f; c10[e] = 0.f; c11[e] = 0.f; }

    auto ldfrag = [](const unsigned short* S, int row, int chunk) -> bf16x8 {
        ushort8v r = *(const ushort8v*)&S[row * BITS + ((chunk ^ (row & 7)) * 8)];
        return __builtin_bit_cast(bf16x8, r);
    };

#pragma unroll
    for (int ks = 0; ks < 4; ++ks) {
        const int ch = ks * 2 + hi;
        bf16x8 a0 = ldfrag(As, wr * 64 +      lrow, ch);
        bf16x8 a1 = ldfrag(As, wr * 64 + 32 + lrow, ch);
        bf16x8 b0 = ldfrag(Bs, wc * 64 +      lrow, ch);
        bf16x8 b1 = ldfrag(Bs, wc * 64 + 32 + lrow, ch);
        c00 = __builtin_amdgcn_mfma_f32_32x32x16_bf16(a0, b0, c00, 0, 0, 0);
        c01 = __builtin_amdgcn_mfma_f32_32x32x16_bf16(a0, b1, c01, 0, 0, 0);
        c10 = __builtin_amdgcn_mfma_f32_32x32x16_bf16(a1, b0, c10, 0, 0, 0);
        c11 = __builtin_amdgcn_mfma_f32_32x32x16_bf16(a1, b1, c11, 0, 0, 0);
    }

    // packed epilogue state
    f32x2 prodA = {1.f, 1.f}, prodS = {1.f, 1.f};
    f32x2 sT = {0.f, 0.f}, sN = {0.f, 0.f}, sTS = {0.f, 0.f}, sNS = {0.f, 0.f};

    if (!diag) {
#pragma unroll
        for (int it = 0; it < 2; ++it) {
            int trow[16];
#pragma unroll
            for (int r = 0; r < 16; ++r)
                trow[r] = tI[wr * 64 + it * 32 + (r & 3) + 8 * (r >> 2) + 4 * hi];
#pragma unroll
            for (int jt = 0; jt < 2; ++jt) {
                const int tc = tJ[wc * 64 + jt * 32 + lrow];
                const f32x16& C = it ? (jt ? c11 : c10) : (jt ? c01 : c00);
#pragma unroll
                for (int r = 0; r < 16; r += 2) {
                    float t0 = C[r], t1 = C[r + 1];
                    float n0 = __uint_as_float(__float_as_uint(t0) | 0x80000000u);
                    float n1 = __uint_as_float(__float_as_uint(t1) | 0x80000000u);
                    f32x2 t2; t2[0] = t0; t2[1] = t1;
                    f32x2 n2; n2[0] = n0; n2[1] = n1;
                    f32x2 u2;
                    if (it == 0) {                         // VALU pipe (Schraudolph)
                        f32x2 sc = n2 * 8388608.0f;
                        u2[0] = __int_as_float((int)sc[0] + SCH_BITS);
                        u2[1] = __int_as_float((int)sc[1] + SCH_BITS);
                    } else {                               // trans pipe (exact 2^n)
                        u2[0] = fexp2(n2[0]);
                        u2[1] = fexp2(n2[1]);
                    }
                    f32x2 mf;
                    mf[0] = (trow[r]     == tc) ? 1.f : 0.f;
                    mf[1] = (trow[r + 1] == tc) ? 1.f : 0.f;
                    prodA = prodA + prodA * u2;
                    prodS = prodS + prodS * (mf * u2);
                    sT  = sT  + t2;
                    sN  = sN  + n2;
                    sTS = sTS + mf * t2;
                    sNS = sNS + mf * n2;
                }
            }
        }
    } else {
#pragma unroll
        for (int it = 0; it < 2; ++it) {
            int trow[16], lrr[16];
#pragma unroll
            for (int r = 0; r < 16; ++r) {
                lrr[r] = wr * 64 + it * 32 + (r & 3) + 8 * (r >> 2) + 4 * hi;
                trow[r] = tI[lrr[r]];
            }
#pragma unroll
            for (int jt = 0; jt < 2; ++jt) {
                const int lc = wc * 64 + jt * 32 + lrow;
                const int tc = tJ[lc];
                const f32x16& C = it ? (jt ? c11 : c10) : (jt ? c01 : c00);
#pragma unroll
                for (int r = 0; r < 16; r += 2) {
                    float t0 = C[r], t1 = C[r + 1];
                    float n0 = __uint_as_float(__float_as_uint(t0) | 0x80000000u);
                    float n1 = __uint_as_float(__float_as_uint(t1) | 0x80000000u);
                    f32x2 t2; t2[0] = t0; t2[1] = t1;
                    f32x2 n2; n2[0] = n0; n2[1] = n1;
                    f32x2 u2;
                    if (it == 0) {
                        f32x2 sc = n2 * 8388608.0f;
                        u2[0] = __int_as_float((int)sc[0] + SCH_BITS);
                        u2[1] = __int_as_float((int)sc[1] + SCH_BITS);
                    } else {
                        u2[0] = fexp2(n2[0]);
                        u2[1] = fexp2(n2[1]);
                    }
                    bool v0 = lc > lrr[r], v1 = lc > lrr[r + 1];
                    f32x2 vf; vf[0] = v0 ? 1.f : 0.f; vf[1] = v1 ? 1.f : 0.f;
                    f32x2 mf;
                    mf[0] = (v0 && trow[r]     == tc) ? 1.f : 0.f;
                    mf[1] = (v1 && trow[r + 1] == tc) ? 1.f : 0.f;
                    prodA = prodA + prodA * (vf * u2);
                    prodS = prodS + prodS * (mf * u2);
                    sT  = sT  + vf * t2;
                    sN  = sN  + vf * n2;
                    sTS = sTS + mf * t2;
                    sNS = sNS + mf * n2;
                }
            }
        }
    }

    // relu-sum = (sum t - sum(-|t|)) / 2
    float s_all  = 0.5f * ((sT[0] + sT[1]) - (sN[0] + sN[1])) + flog2(prodA[0] * prodA[1]);
    float s_same = 0.5f * ((sTS[0] + sTS[1]) - (sNS[0] + sNS[1])) + flog2(prodS[0] * prodS[1]);
    float t_same = sTS[0] + sTS[1];

#pragma unroll
    for (int d = 32; d > 0; d >>= 1) {
        s_all  += __shfl_xor(s_all,  d, 64);
        s_same += __shfl_xor(s_same, d, 64);
        t_same += __shfl_xor(t_same, d, 64);
    }
    if (lane == 0) { red[wave] = s_all; red[4 + wave] = s_same; red[8 + wave] = t_same; }

    {   // cls softmax on preloaded registers
        float nll = 0.f;
        if (crow < NPTS) {
            float m = fmaxf(cx1, cx2);
#pragma unroll
            for (int d = 32; d > 0; d >>= 1) m = fmaxf(m, __shfl_xor(m, d, 64));
            float e = __expf(cx1 - m) + ((lane + 64 < NCLS) ? __expf(cx2 - m) : 0.f);
#pragma unroll
            for (int d = 32; d > 0; d >>= 1) e += __shfl_xor(e, d, 64);
            if (lane == 0) nll = m + __logf(e) - cxt;
        }
        if (lane == 0) red[12 + wave] = nll;
    }
    __syncthreads();
    if (tid == 0) {
        ws[p]              = (double)red[0]  + (double)red[1]  + (double)red[2]  + (double)red[3];
        ws[NPAIRS + p]     = (double)red[4]  + (double)red[5]  + (double)red[6]  + (double)red[7];
        ws[2 * NPAIRS + p] = (double)red[8]  + (double)red[9]  + (double)red[10] + (double)red[11];
        ws[WS_CLS + p]     = (double)red[12] + (double)red[13] + (double)red[14] + (double)red[15];
    }
}

// ---------------------------------------------------------------------------
// Finalize: histogram -> S0/S1 weights; double reduction; ln2 fold here.
// ---------------------------------------------------------------------------
__global__ __launch_bounds__(256) void final_kernel(const int* __restrict__ tgt,
                                                    const double* __restrict__ ws,
                                                    float* __restrict__ out) {
    __shared__ int hist[NCLS];
    __shared__ double r0[256], r1[256], r2[256], rc[256];
    const int tid = threadIdx.x;

    for (int i = tid; i < NCLS; i += 256) hist[i] = 0;
    __syncthreads();
    for (int i = tid; i < NPTS; i += 256) atomicAdd(&hist[tgt[i]], 1);
    __syncthreads();

    double a = 0.0, s = 0.0, t = 0.0, c = 0.0;
    for (int i = tid; i < NPAIRS; i += 256) {
        a += ws[i];
        s += ws[NPAIRS + i];
        t += ws[2 * NPAIRS + i];
        c += ws[WS_CLS + i];
    }
    r0[tid] = a; r1[tid] = s; r2[tid] = t; rc[tid] = c;
    __syncthreads();
    for (int sdt = 128; sdt > 0; sdt >>= 1) {
        if (tid < sdt) {
            r0[tid] += r0[tid + sdt];
            r1[tid] += r1[tid + sdt];
            r2[tid] += r2[tid + sdt];
            rc[tid] += rc[tid + sdt];
        }
        __syncthreads();
    }

    if (tid == 0) {
        double n_pos = 0.0;
        for (int k = 0; k < NCLS; k++) {
            double cc = (double)hist[k];
            n_pos += cc * cc;
        }
        const double Nd = (double)NPTS;
        double S1 = n_pos - Nd;
        double S0 = Nd * Nd - n_pos;
        if (S0 == 0.0) S0 = 1.0;
        if (S1 == 0.0) S1 = 1.0;
        const double S = S0 + S1;
        const double sum_lower =
            ((S / S0) * (r0[0] - r1[0]) + (S / S1) * (r1[0] - r2[0])) * LN2;
        const double count = Nd * (Nd - 1.0) * 0.5;
        const double hash_loss = sum_lower / count;
        const double cls_loss  = rc[0] / Nd;
        const double loss = 1.0 * cls_loss + 0.01 * hash_loss;
        out[0] = (float)hash_loss;
        out[1] = (float)cls_loss;
        out[2] = (float)loss;
    }
}

// ---------------------------------------------------------------------------
extern "C" void kernel_launch(void* const* d_in, const int* in_sizes, int n_in,
                              void* d_out, int out_size, void* d_ws, size_t ws_size,
                              hipStream_t stream) {
    const float* H   = (const float*)d_in[0];
    const float* X   = (const float*)d_in[1];
    const int*   tgt = (const int*)d_in[2];
    float* out = (float*)d_out;
    double* wsd = (double*)d_ws;

    hash_cls_kernel<<<NPAIRS, 256, 0, stream>>>(H, X, tgt, wsd);
    final_kernel<<<1, 256, 0, stream>>>(tgt, wsd, out);
}

// Round 20
// 31.538 us; speedup vs baseline: 1.2020x; 1.0218x over previous
//
#include <hip/hip_runtime.h>
#include <math.h>

#define NPTS   8192
#define BITS   64
#define NCLS   101
#define TILE   128
#define NT     (NPTS / TILE)            // 64
#define NPAIRS (NT * (NT + 1) / 2)      // 2080
#define WS_CLS (3 * NPAIRS)
#define SCALE  0.84932184f              // sqrt(0.5*log2 e): acc = t = theta*log2(e)
#define LN2    0.6931471805599453

// ws doubles: [0,N) sp_all(log2 units) | [N,2N) sp_same | [2N,3N) t_same | [3N,4N) cls

typedef short    bf16x8   __attribute__((ext_vector_type(8)));
typedef unsigned short ushort8v __attribute__((ext_vector_type(8)));
typedef float    f32x16  __attribute__((ext_vector_type(16)));
typedef float    f32x2   __attribute__((ext_vector_type(2)));

__device__ __forceinline__ float flog2(float x) {
    float r; asm("v_log_f32 %0, %1" : "=v"(r) : "v"(x)); return r;
}
__device__ __forceinline__ float fexp2(float x) {        // trans pipe: exact 2^x
    float r; asm("v_exp_f32 %0, %1" : "=v"(r) : "v"(x)); return r;
}
__device__ __forceinline__ unsigned cvt_pk_bf16(float lo, float hi) {
    unsigned r;
    asm("v_cvt_pk_bf16_f32 %0, %1, %2" : "=v"(r) : "v"(lo), "v"(hi));
    return r;
}
__device__ __forceinline__ void tile_map(int p, int& ti, int& tj) {
    float disc = (2.0f * NT + 1.0f) * (2.0f * NT + 1.0f) - 8.0f * (float)p;
    ti = (int)(((2.0f * NT + 1.0f) - sqrtf(disc)) * 0.5f);
    if (ti < 0) ti = 0;
    if (ti >= NT) ti = NT - 1;
    while (ti > 0 && (ti * NT - ti * (ti - 1) / 2) > p) ti--;
    while ((ti + 1) * NT - (ti + 1) * ti / 2 <= p) ti++;
    tj = ti + (p - (ti * NT - ti * (ti - 1) / 2));
}

// ---------------------------------------------------------------------------
// Fused hash tile + cls rows. (256,4); 2-batch spill-free staging; epilogue
// u = v_exp_f32(-|t|) on the TRANS pipe (1 issue-op/elem, runs parallel to
// the packed-VALU accumulation stream).
// ---------------------------------------------------------------------------
__global__ __launch_bounds__(256, 4) void hash_cls_kernel(const float* __restrict__ H,
                                                          const float* __restrict__ X,
                                                          const int* __restrict__ tgt,
                                                          double* __restrict__ ws) {
    __shared__ unsigned short As[TILE * BITS];
    __shared__ unsigned short Bs[TILE * BITS];
    __shared__ int tI[TILE];
    __shared__ int tJ[TILE];
    __shared__ float red[16];

    const int tid = threadIdx.x;
    const int p = blockIdx.x;
    int ti, tj; tile_map(p, ti, tj);
    const int i0 = ti * TILE, j0 = tj * TILE;
    const bool diag = (ti == tj);
    const int lane = tid & 63, wave = tid >> 6;

    if (tid < TILE) { tI[tid] = tgt[i0 + tid]; tJ[tid] = tgt[j0 + tid]; }

    // ---- cls loads hoisted ----
    const int crow = p * 4 + wave;
    float cx1 = -INFINITY, cx2 = -INFINITY, cxt = 0.f;
    if (crow < NPTS) {
        const float* x = X + (size_t)crow * NCLS;
        cx1 = x[lane];
        cx2 = (lane + 64 < NCLS) ? x[lane + 64] : -INFINITY;
        cxt = x[tgt[crow]];
    }

    // ---- staging: 2 batches of 4 float4-pairs (32 VGPRs in flight) ----
#pragma unroll
    for (int bb = 0; bb < 2; ++bb) {
        float4 buf0[4], buf1[4];
#pragma unroll
        for (int it = 0; it < 4; ++it) {
            const int idx  = tid + (bb * 4 + it) * 256;
            const int half = idx >> 10;
            const int lid  = idx & 1023;
            const int row  = lid >> 3;
            const int c    = lid & 7;
            const float* src = H + (size_t)((half ? j0 : i0) + row) * BITS + c * 8;
            buf0[it] = *(const float4*)src;
            buf1[it] = *(const float4*)(src + 4);
        }
#pragma unroll
        for (int it = 0; it < 4; ++it) {
            const int idx  = tid + (bb * 4 + it) * 256;
            const int half = idx >> 10;
            const int lid  = idx & 1023;
            const int row  = lid >> 3;
            const int c    = lid & 7;
            uint4 v;
            v.x = cvt_pk_bf16(buf0[it].x * SCALE, buf0[it].y * SCALE);
            v.y = cvt_pk_bf16(buf0[it].z * SCALE, buf0[it].w * SCALE);
            v.z = cvt_pk_bf16(buf1[it].x * SCALE, buf1[it].y * SCALE);
            v.w = cvt_pk_bf16(buf1[it].z * SCALE, buf1[it].w * SCALE);
            unsigned short* dst = half ? Bs : As;
            *(uint4*)&dst[row * BITS + ((c ^ (row & 7)) * 8)] = v;
        }
    }
    __syncthreads();

    const int wr = wave >> 1, wc = wave & 1;
    const int lrow = lane & 31, hi = lane >> 5;

    f32x16 c00, c01, c10, c11;
#pragma unroll
    for (int e = 0; e < 16; ++e) { c00[e] = 0.f; c01[e] = 0.f; c10[e] = 0.f; c11[e] = 0.f; }

    auto ldfrag = [](const unsigned short* S, int row, int chunk) -> bf16x8 {
        ushort8v r = *(const ushort8v*)&S[row * BITS + ((chunk ^ (row & 7)) * 8)];
        return __builtin_bit_cast(bf16x8, r);
    };

#pragma unroll
    for (int ks = 0; ks < 4; ++ks) {
        const int ch = ks * 2 + hi;
        bf16x8 a0 = ldfrag(As, wr * 64 +      lrow, ch);
        bf16x8 a1 = ldfrag(As, wr * 64 + 32 + lrow, ch);
        bf16x8 b0 = ldfrag(Bs, wc * 64 +      lrow, ch);
        bf16x8 b1 = ldfrag(Bs, wc * 64 + 32 + lrow, ch);
        c00 = __builtin_amdgcn_mfma_f32_32x32x16_bf16(a0, b0, c00, 0, 0, 0);
        c01 = __builtin_amdgcn_mfma_f32_32x32x16_bf16(a0, b1, c01, 0, 0, 0);
        c10 = __builtin_amdgcn_mfma_f32_32x32x16_bf16(a1, b0, c10, 0, 0, 0);
        c11 = __builtin_amdgcn_mfma_f32_32x32x16_bf16(a1, b1, c11, 0, 0, 0);
    }

    // packed epilogue state
    f32x2 prodA = {1.f, 1.f}, prodS = {1.f, 1.f};
    f32x2 sT = {0.f, 0.f}, sN = {0.f, 0.f}, sTS = {0.f, 0.f}, sNS = {0.f, 0.f};

    if (!diag) {
#pragma unroll
        for (int it = 0; it < 2; ++it) {
            int trow[16];
#pragma unroll
            for (int r = 0; r < 16; ++r)
                trow[r] = tI[wr * 64 + it * 32 + (r & 3) + 8 * (r >> 2) + 4 * hi];
#pragma unroll
            for (int jt = 0; jt < 2; ++jt) {
                const int tc = tJ[wc * 64 + jt * 32 + lrow];
                const f32x16& C = it ? (jt ? c11 : c10) : (jt ? c01 : c00);
#pragma unroll
                for (int r = 0; r < 16; r += 2) {
                    float t0 = C[r], t1 = C[r + 1];
                    float n0 = __uint_as_float(__float_as_uint(t0) | 0x80000000u);
                    float n1 = __uint_as_float(__float_as_uint(t1) | 0x80000000u);
                    f32x2 t2; t2[0] = t0; t2[1] = t1;
                    f32x2 n2; n2[0] = n0; n2[1] = n1;
                    f32x2 u2;                               // trans pipe (exact 2^n)
                    u2[0] = fexp2(n0);
                    u2[1] = fexp2(n1);
                    f32x2 mf;
                    mf[0] = (trow[r]     == tc) ? 1.f : 0.f;
                    mf[1] = (trow[r + 1] == tc) ? 1.f : 0.f;
                    prodA = prodA + prodA * u2;
                    prodS = prodS + prodS * (mf * u2);
                    sT  = sT  + t2;
                    sN  = sN  + n2;
                    sTS = sTS + mf * t2;
                    sNS = sNS + mf * n2;
                }
            }
        }
    } else {
#pragma unroll
        for (int it = 0; it < 2; ++it) {
            int trow[16], lrr[16];
#pragma unroll
            for (int r = 0; r < 16; ++r) {
                lrr[r] = wr * 64 + it * 32 + (r & 3) + 8 * (r >> 2) + 4 * hi;
                trow[r] = tI[lrr[r]];
            }
#pragma unroll
            for (int jt = 0; jt < 2; ++jt) {
                const int lc = wc * 64 + jt * 32 + lrow;
                const int tc = tJ[lc];
                const f32x16& C = it ? (jt ? c11 : c10) : (jt ? c01 : c00);
#pragma unroll
                for (int r = 0; r < 16; r += 2) {
                    float t0 = C[r], t1 = C[r + 1];
                    float n0 = __uint_as_float(__float_as_uint(t0) | 0x80000000u);
                    float n1 = __uint_as_float(__float_as_uint(t1) | 0x80000000u);
                    f32x2 t2; t2[0] = t0; t2[1] = t1;
                    f32x2 n2; n2[0] = n0; n2[1] = n1;
                    f32x2 u2;
                    u2[0] = fexp2(n0);
                    u2[1] = fexp2(n1);
                    bool v0 = lc > lrr[r], v1 = lc > lrr[r + 1];
                    f32x2 vf; vf[0] = v0 ? 1.f : 0.f; vf[1] = v1 ? 1.f : 0.f;
                    f32x2 mf;
                    mf[0] = (v0 && trow[r]     == tc) ? 1.f : 0.f;
                    mf[1] = (v1 && trow[r + 1] == tc) ? 1.f : 0.f;
                    prodA = prodA + prodA * (vf * u2);
                    prodS = prodS + prodS * (mf * u2);
                    sT  = sT  + vf * t2;
                    sN  = sN  + vf * n2;
                    sTS = sTS + mf * t2;
                    sNS = sNS + mf * n2;
                }
            }
        }
    }

    // relu-sum = (sum t - sum(-|t|)) / 2
    float s_all  = 0.5f * ((sT[0] + sT[1]) - (sN[0] + sN[1])) + flog2(prodA[0] * prodA[1]);
    float s_same = 0.5f * ((sTS[0] + sTS[1]) - (sNS[0] + sNS[1])) + flog2(prodS[0] * prodS[1]);
    float t_same = sTS[0] + sTS[1];

#pragma unroll
    for (int d = 32; d > 0; d >>= 1) {
        s_all  += __shfl_xor(s_all,  d, 64);
        s_same += __shfl_xor(s_same, d, 64);
        t_same += __shfl_xor(t_same, d, 64);
    }
    if (lane == 0) { red[wave] = s_all; red[4 + wave] = s_same; red[8 + wave] = t_same; }

    {   // cls softmax on preloaded registers
        float nll = 0.f;
        if (crow < NPTS) {
            float m = fmaxf(cx1, cx2);
#pragma unroll
            for (int d = 32; d > 0; d >>= 1) m = fmaxf(m, __shfl_xor(m, d, 64));
            float e = __expf(cx1 - m) + ((lane + 64 < NCLS) ? __expf(cx2 - m) : 0.f);
#pragma unroll
            for (int d = 32; d > 0; d >>= 1) e += __shfl_xor(e, d, 64);
            if (lane == 0) nll = m + __logf(e) - cxt;
        }
        if (lane == 0) red[12 + wave] = nll;
    }
    __syncthreads();
    if (tid == 0) {
        ws[p]              = (double)red[0]  + (double)red[1]  + (double)red[2]  + (double)red[3];
        ws[NPAIRS + p]     = (double)red[4]  + (double)red[5]  + (double)red[6]  + (double)red[7];
        ws[2 * NPAIRS + p] = (double)red[8]  + (double)red[9]  + (double)red[10] + (double)red[11];
        ws[WS_CLS + p]     = (double)red[12] + (double)red[13] + (double)red[14] + (double)red[15];
    }
}

// ---------------------------------------------------------------------------
// Finalize: histogram -> S0/S1 weights; double reduction; ln2 fold here.
// ---------------------------------------------------------------------------
__global__ __launch_bounds__(256) void final_kernel(const int* __restrict__ tgt,
                                                    const double* __restrict__ ws,
                                                    float* __restrict__ out) {
    __shared__ int hist[NCLS];
    __shared__ double r0[256], r1[256], r2[256], rc[256];
    const int tid = threadIdx.x;

    for (int i = tid; i < NCLS; i += 256) hist[i] = 0;
    __syncthreads();
    for (int i = tid; i < NPTS; i += 256) atomicAdd(&hist[tgt[i]], 1);
    __syncthreads();

    double a = 0.0, s = 0.0, t = 0.0, c = 0.0;
    for (int i = tid; i < NPAIRS; i += 256) {
        a += ws[i];
        s += ws[NPAIRS + i];
        t += ws[2 * NPAIRS + i];
        c += ws[WS_CLS + i];
    }
    r0[tid] = a; r1[tid] = s; r2[tid] = t; rc[tid] = c;
    __syncthreads();
    for (int sdt = 128; sdt > 0; sdt >>= 1) {
        if (tid < sdt) {
            r0[tid] += r0[tid + sdt];
            r1[tid] += r1[tid + sdt];
            r2[tid] += r2[tid + sdt];
            rc[tid] += rc[tid + sdt];
        }
        __syncthreads();
    }

    if (tid == 0) {
        double n_pos = 0.0;
        for (int k = 0; k < NCLS; k++) {
            double cc = (double)hist[k];
            n_pos += cc * cc;
        }
        const double Nd = (double)NPTS;
        double S1 = n_pos - Nd;
        double S0 = Nd * Nd - n_pos;
        if (S0 == 0.0) S0 = 1.0;
        if (S1 == 0.0) S1 = 1.0;
        const double S = S0 + S1;
        const double sum_lower =
            ((S / S0) * (r0[0] - r1[0]) + (S / S1) * (r1[0] - r2[0])) * LN2;
        const double count = Nd * (Nd - 1.0) * 0.5;
        const double hash_loss = sum_lower / count;
        const double cls_loss  = rc[0] / Nd;
        const double loss = 1.0 * cls_loss + 0.01 * hash_loss;
        out[0] = (float)hash_loss;
        out[1] = (float)cls_loss;
        out[2] = (float)loss;
    }
}

// ---------------------------------------------------------------------------
extern "C" void kernel_launch(void* const* d_in, const int* in_sizes, int n_in,
                              void* d_out, int out_size, void* d_ws, size_t ws_size,
                              hipStream_t stream) {
    const float* H   = (const float*)d_in[0];
    const float* X   = (const float*)d_in[1];
    const int*   tgt = (const int*)d_in[2];
    float* out = (float*)d_out;
    double* wsd = (double*)d_ws;

    hash_cls_kernel<<<NPAIRS, 256, 0, stream>>>(H, X, tgt, wsd);
    final_kernel<<<1, 256, 0, stream>>>(tgt, wsd, out);
}

// Round 21
// 28.386 us; speedup vs baseline: 1.3355x; 1.1110x over previous
//
#include <hip/hip_runtime.h>
#include <math.h>

#define NPTS   8192
#define BITS   64
#define NCLS   101
#define TILE   128
#define NT     (NPTS / TILE)            // 64
#define NPAIRS (NT * (NT + 1) / 2)      // 2080
#define SCALE  0.84932184f              // sqrt(0.5*log2 e): acc = t = theta*log2(e)
#define LN2    0.6931471805599453

// ws doubles: [0,N) sp_all | [N,2N) sp_same | [2N,3N) t_same | [3N,4N) cnt_same | [4N,5N) cls

typedef short    bf16x8   __attribute__((ext_vector_type(8)));
typedef unsigned short ushort8v __attribute__((ext_vector_type(8)));
typedef float    f32x16  __attribute__((ext_vector_type(16)));
typedef float    f32x2   __attribute__((ext_vector_type(2)));

__device__ __forceinline__ float flog2(float x) {
    float r; asm("v_log_f32 %0, %1" : "=v"(r) : "v"(x)); return r;
}
__device__ __forceinline__ float fexp2(float x) {        // trans pipe: exact 2^x
    float r; asm("v_exp_f32 %0, %1" : "=v"(r) : "v"(x)); return r;
}
__device__ __forceinline__ unsigned cvt_pk_bf16(float lo, float hi) {
    unsigned r;
    asm("v_cvt_pk_bf16_f32 %0, %1, %2" : "=v"(r) : "v"(lo), "v"(hi));
    return r;
}
__device__ __forceinline__ void tile_map(int p, int& ti, int& tj) {
    float disc = (2.0f * NT + 1.0f) * (2.0f * NT + 1.0f) - 8.0f * (float)p;
    ti = (int)(((2.0f * NT + 1.0f) - sqrtf(disc)) * 0.5f);
    if (ti < 0) ti = 0;
    if (ti >= NT) ti = NT - 1;
    while (ti > 0 && (ti * NT - ti * (ti - 1) / 2) > p) ti--;
    while ((ti + 1) * NT - (ti + 1) * ti / 2 <= p) ti++;
    tj = ti + (p - (ti * NT - ti * (ti - 1) / 2));
}

// ---------------------------------------------------------------------------
// Fused hash tile + cls rows. (256,4); 2-batch spill-free staging; trans-pipe
// u = v_exp_f32(-|t|); packed-VALU accumulation incl. same-class pair count
// (so the finalize needs no histogram pass).
// ---------------------------------------------------------------------------
__global__ __launch_bounds__(256, 4) void hash_cls_kernel(const float* __restrict__ H,
                                                          const float* __restrict__ X,
                                                          const int* __restrict__ tgt,
                                                          double* __restrict__ ws) {
    __shared__ unsigned short As[TILE * BITS];
    __shared__ unsigned short Bs[TILE * BITS];
    __shared__ int tI[TILE];
    __shared__ int tJ[TILE];
    __shared__ float red[20];

    const int tid = threadIdx.x;
    const int p = blockIdx.x;
    int ti, tj; tile_map(p, ti, tj);
    const int i0 = ti * TILE, j0 = tj * TILE;
    const bool diag = (ti == tj);
    const int lane = tid & 63, wave = tid >> 6;

    if (tid < TILE) { tI[tid] = tgt[i0 + tid]; tJ[tid] = tgt[j0 + tid]; }

    // ---- cls loads hoisted ----
    const int crow = p * 4 + wave;
    float cx1 = -INFINITY, cx2 = -INFINITY, cxt = 0.f;
    if (crow < NPTS) {
        const float* x = X + (size_t)crow * NCLS;
        cx1 = x[lane];
        cx2 = (lane + 64 < NCLS) ? x[lane + 64] : -INFINITY;
        cxt = x[tgt[crow]];
    }

    // ---- staging: 2 batches of 4 float4-pairs (32 VGPRs in flight) ----
#pragma unroll
    for (int bb = 0; bb < 2; ++bb) {
        float4 buf0[4], buf1[4];
#pragma unroll
        for (int it = 0; it < 4; ++it) {
            const int idx  = tid + (bb * 4 + it) * 256;
            const int half = idx >> 10;
            const int lid  = idx & 1023;
            const int row  = lid >> 3;
            const int c    = lid & 7;
            const float* src = H + (size_t)((half ? j0 : i0) + row) * BITS + c * 8;
            buf0[it] = *(const float4*)src;
            buf1[it] = *(const float4*)(src + 4);
        }
#pragma unroll
        for (int it = 0; it < 4; ++it) {
            const int idx  = tid + (bb * 4 + it) * 256;
            const int half = idx >> 10;
            const int lid  = idx & 1023;
            const int row  = lid >> 3;
            const int c    = lid & 7;
            uint4 v;
            v.x = cvt_pk_bf16(buf0[it].x * SCALE, buf0[it].y * SCALE);
            v.y = cvt_pk_bf16(buf0[it].z * SCALE, buf0[it].w * SCALE);
            v.z = cvt_pk_bf16(buf1[it].x * SCALE, buf1[it].y * SCALE);
            v.w = cvt_pk_bf16(buf1[it].z * SCALE, buf1[it].w * SCALE);
            unsigned short* dst = half ? Bs : As;
            *(uint4*)&dst[row * BITS + ((c ^ (row & 7)) * 8)] = v;
        }
    }
    __syncthreads();

    const int wr = wave >> 1, wc = wave & 1;
    const int lrow = lane & 31, hi = lane >> 5;

    f32x16 c00, c01, c10, c11;
#pragma unroll
    for (int e = 0; e < 16; ++e) { c00[e] = 0.f; c01[e] = 0.f; c10[e] = 0.f; c11[e] = 0.f; }

    auto ldfrag = [](const unsigned short* S, int row, int chunk) -> bf16x8 {
        ushort8v r = *(const ushort8v*)&S[row * BITS + ((chunk ^ (row & 7)) * 8)];
        return __builtin_bit_cast(bf16x8, r);
    };

#pragma unroll
    for (int ks = 0; ks < 4; ++ks) {
        const int ch = ks * 2 + hi;
        bf16x8 a0 = ldfrag(As, wr * 64 +      lrow, ch);
        bf16x8 a1 = ldfrag(As, wr * 64 + 32 + lrow, ch);
        bf16x8 b0 = ldfrag(Bs, wc * 64 +      lrow, ch);
        bf16x8 b1 = ldfrag(Bs, wc * 64 + 32 + lrow, ch);
        c00 = __builtin_amdgcn_mfma_f32_32x32x16_bf16(a0, b0, c00, 0, 0, 0);
        c01 = __builtin_amdgcn_mfma_f32_32x32x16_bf16(a0, b1, c01, 0, 0, 0);
        c10 = __builtin_amdgcn_mfma_f32_32x32x16_bf16(a1, b0, c10, 0, 0, 0);
        c11 = __builtin_amdgcn_mfma_f32_32x32x16_bf16(a1, b1, c11, 0, 0, 0);
    }

    // packed epilogue state (+ same-class count)
    f32x2 prodA = {1.f, 1.f}, prodS = {1.f, 1.f};
    f32x2 sT = {0.f, 0.f}, sN = {0.f, 0.f}, sTS = {0.f, 0.f}, sNS = {0.f, 0.f};
    f32x2 sC = {0.f, 0.f};

    if (!diag) {
#pragma unroll
        for (int it = 0; it < 2; ++it) {
            int trow[16];
#pragma unroll
            for (int r = 0; r < 16; ++r)
                trow[r] = tI[wr * 64 + it * 32 + (r & 3) + 8 * (r >> 2) + 4 * hi];
#pragma unroll
            for (int jt = 0; jt < 2; ++jt) {
                const int tc = tJ[wc * 64 + jt * 32 + lrow];
                const f32x16& C = it ? (jt ? c11 : c10) : (jt ? c01 : c00);
#pragma unroll
                for (int r = 0; r < 16; r += 2) {
                    float t0 = C[r], t1 = C[r + 1];
                    float n0 = __uint_as_float(__float_as_uint(t0) | 0x80000000u);
                    float n1 = __uint_as_float(__float_as_uint(t1) | 0x80000000u);
                    f32x2 t2; t2[0] = t0; t2[1] = t1;
                    f32x2 n2; n2[0] = n0; n2[1] = n1;
                    f32x2 u2;                               // trans pipe (exact 2^n)
                    u2[0] = fexp2(n0);
                    u2[1] = fexp2(n1);
                    f32x2 mf;
                    mf[0] = (trow[r]     == tc) ? 1.f : 0.f;
                    mf[1] = (trow[r + 1] == tc) ? 1.f : 0.f;
                    prodA = prodA + prodA * u2;
                    prodS = prodS + prodS * (mf * u2);
                    sT  = sT  + t2;
                    sN  = sN  + n2;
                    sTS = sTS + mf * t2;
                    sNS = sNS + mf * n2;
                    sC  = sC  + mf;
                }
            }
        }
    } else {
#pragma unroll
        for (int it = 0; it < 2; ++it) {
            int trow[16], lrr[16];
#pragma unroll
            for (int r = 0; r < 16; ++r) {
                lrr[r] = wr * 64 + it * 32 + (r & 3) + 8 * (r >> 2) + 4 * hi;
                trow[r] = tI[lrr[r]];
            }
#pragma unroll
            for (int jt = 0; jt < 2; ++jt) {
                const int lc = wc * 64 + jt * 32 + lrow;
                const int tc = tJ[lc];
                const f32x16& C = it ? (jt ? c11 : c10) : (jt ? c01 : c00);
#pragma unroll
                for (int r = 0; r < 16; r += 2) {
                    float t0 = C[r], t1 = C[r + 1];
                    float n0 = __uint_as_float(__float_as_uint(t0) | 0x80000000u);
                    float n1 = __uint_as_float(__float_as_uint(t1) | 0x80000000u);
                    f32x2 t2; t2[0] = t0; t2[1] = t1;
                    f32x2 n2; n2[0] = n0; n2[1] = n1;
                    f32x2 u2;
                    u2[0] = fexp2(n0);
                    u2[1] = fexp2(n1);
                    bool v0 = lc > lrr[r], v1 = lc > lrr[r + 1];
                    f32x2 vf; vf[0] = v0 ? 1.f : 0.f; vf[1] = v1 ? 1.f : 0.f;
                    f32x2 mf;
                    mf[0] = (v0 && trow[r]     == tc) ? 1.f : 0.f;
                    mf[1] = (v1 && trow[r + 1] == tc) ? 1.f : 0.f;
                    prodA = prodA + prodA * (vf * u2);
                    prodS = prodS + prodS * (mf * u2);
                    sT  = sT  + vf * t2;
                    sN  = sN  + vf * n2;
                    sTS = sTS + mf * t2;
                    sNS = sNS + mf * n2;
                    sC  = sC  + mf;
                }
            }
        }
    }

    // relu-sum = (sum t - sum(-|t|)) / 2
    float s_all  = 0.5f * ((sT[0] + sT[1]) - (sN[0] + sN[1])) + flog2(prodA[0] * prodA[1]);
    float s_same = 0.5f * ((sTS[0] + sTS[1]) - (sNS[0] + sNS[1])) + flog2(prodS[0] * prodS[1]);
    float t_same = sTS[0] + sTS[1];
    float c_same = sC[0] + sC[1];

#pragma unroll
    for (int d = 32; d > 0; d >>= 1) {
        s_all  += __shfl_xor(s_all,  d, 64);
        s_same += __shfl_xor(s_same, d, 64);
        t_same += __shfl_xor(t_same, d, 64);
        c_same += __shfl_xor(c_same, d, 64);
    }
    if (lane == 0) {
        red[wave] = s_all; red[4 + wave] = s_same;
        red[8 + wave] = t_same; red[12 + wave] = c_same;
    }

    {   // cls softmax on preloaded registers
        float nll = 0.f;
        if (crow < NPTS) {
            float m = fmaxf(cx1, cx2);
#pragma unroll
            for (int d = 32; d > 0; d >>= 1) m = fmaxf(m, __shfl_xor(m, d, 64));
            float e = __expf(cx1 - m) + ((lane + 64 < NCLS) ? __expf(cx2 - m) : 0.f);
#pragma unroll
            for (int d = 32; d > 0; d >>= 1) e += __shfl_xor(e, d, 64);
            if (lane == 0) nll = m + __logf(e) - cxt;
        }
        if (lane == 0) red[16 + wave] = nll;
    }
    __syncthreads();
    if (tid == 0) {
        ws[p]              = (double)red[0]  + (double)red[1]  + (double)red[2]  + (double)red[3];
        ws[NPAIRS + p]     = (double)red[4]  + (double)red[5]  + (double)red[6]  + (double)red[7];
        ws[2 * NPAIRS + p] = (double)red[8]  + (double)red[9]  + (double)red[10] + (double)red[11];
        ws[3 * NPAIRS + p] = (double)red[12] + (double)red[13] + (double)red[14] + (double)red[15];
        ws[4 * NPAIRS + p] = (double)red[16] + (double)red[17] + (double)red[18] + (double)red[19];
    }
}

// ---------------------------------------------------------------------------
// Finalize (1024 threads, NO histogram): S1 = 2 * cnt_same; double reduction;
// ln2 fold; 3 scalars.
// ---------------------------------------------------------------------------
__global__ __launch_bounds__(1024) void final_kernel(const double* __restrict__ ws,
                                                     float* __restrict__ out) {
    __shared__ double r0[1024], r1[1024], r2[1024], r3[1024], rc[1024];
    const int tid = threadIdx.x;

    double a = 0.0, s = 0.0, t = 0.0, n = 0.0, c = 0.0;
    for (int i = tid; i < NPAIRS; i += 1024) {
        a += ws[i];
        s += ws[NPAIRS + i];
        t += ws[2 * NPAIRS + i];
        n += ws[3 * NPAIRS + i];
        c += ws[4 * NPAIRS + i];
    }
    r0[tid] = a; r1[tid] = s; r2[tid] = t; r3[tid] = n; rc[tid] = c;
    __syncthreads();
    for (int sd = 512; sd > 0; sd >>= 1) {
        if (tid < sd) {
            r0[tid] += r0[tid + sd];
            r1[tid] += r1[tid + sd];
            r2[tid] += r2[tid + sd];
            r3[tid] += r3[tid + sd];
            rc[tid] += rc[tid + sd];
        }
        __syncthreads();
    }

    if (tid == 0) {
        const double Nd = (double)NPTS;
        double S1 = 2.0 * r3[0];                 // n_pos - N (exact)
        double S0 = Nd * Nd - (S1 + Nd);
        if (S0 == 0.0) S0 = 1.0;
        if (S1 == 0.0) S1 = 1.0;
        const double S = S0 + S1;
        const double sum_lower =
            ((S / S0) * (r0[0] - r1[0]) + (S / S1) * (r1[0] - r2[0])) * LN2;
        const double count = Nd * (Nd - 1.0) * 0.5;
        const double hash_loss = sum_lower / count;
        const double cls_loss  = rc[0] / Nd;
        const double loss = 1.0 * cls_loss + 0.01 * hash_loss;
        out[0] = (float)hash_loss;
        out[1] = (float)cls_loss;
        out[2] = (float)loss;
    }
}

// ---------------------------------------------------------------------------
extern "C" void kernel_launch(void* const* d_in, const int* in_sizes, int n_in,
                              void* d_out, int out_size, void* d_ws, size_t ws_size,
                              hipStream_t stream) {
    const float* H   = (const float*)d_in[0];
    const float* X   = (const float*)d_in[1];
    const int*   tgt = (const int*)d_in[2];
    float* out = (float*)d_out;
    double* wsd = (double*)d_ws;

    hash_cls_kernel<<<NPAIRS, 256, 0, stream>>>(H, X, tgt, wsd);
    final_kernel<<<1, 1024, 0, stream>>>(wsd, out);
}

// Round 22
// 28.260 us; speedup vs baseline: 1.3414x; 1.0045x over previous
//
#include <hip/hip_runtime.h>
#include <math.h>

#define NPTS   8192
#define BITS   64
#define NCLS   101
#define TILE   128
#define NT     (NPTS / TILE)            // 64
#define NPAIRS (NT * (NT + 1) / 2)      // 2080
#define SCALE  0.84932184f              // sqrt(0.5*log2 e): acc = t = theta*log2(e)
#define LN2    0.6931471805599453

// ws doubles: [0,N) sp_all | [N,2N) sp_same | [2N,3N) t_same | [3N,4N) cnt_same | [4N,5N) cls

typedef short    bf16x8   __attribute__((ext_vector_type(8)));
typedef unsigned short ushort8v __attribute__((ext_vector_type(8)));
typedef float    f32x16  __attribute__((ext_vector_type(16)));
typedef float    f32x2   __attribute__((ext_vector_type(2)));

__device__ __forceinline__ float flog2(float x) {
    float r; asm("v_log_f32 %0, %1" : "=v"(r) : "v"(x)); return r;
}
__device__ __forceinline__ float fexp2(float x) {        // trans pipe: exact 2^x
    float r; asm("v_exp_f32 %0, %1" : "=v"(r) : "v"(x)); return r;
}
__device__ __forceinline__ unsigned cvt_pk_bf16(float lo, float hi) {
    unsigned r;
    asm("v_cvt_pk_bf16_f32 %0, %1, %2" : "=v"(r) : "v"(lo), "v"(hi));
    return r;
}
__device__ __forceinline__ void tile_map(int p, int& ti, int& tj) {
    float disc = (2.0f * NT + 1.0f) * (2.0f * NT + 1.0f) - 8.0f * (float)p;
    ti = (int)(((2.0f * NT + 1.0f) - sqrtf(disc)) * 0.5f);
    if (ti < 0) ti = 0;
    if (ti >= NT) ti = NT - 1;
    while (ti > 0 && (ti * NT - ti * (ti - 1) / 2) > p) ti--;
    while ((ti + 1) * NT - (ti + 1) * ti / 2 <= p) ti++;
    tj = ti + (p - (ti * NT - ti * (ti - 1) / 2));
}

// ---------------------------------------------------------------------------
// Fused hash tile + cls rows. (256,4); 2-batch spill-free staging; trans-pipe
// u = v_exp_f32(-|t|). Epilogue: split product chains (2x shallower deps) +
// int4-vectorized trow LDS reads (ds_read_b128), pair-count accumulator.
// ---------------------------------------------------------------------------
__global__ __launch_bounds__(256, 4) void hash_cls_kernel(const float* __restrict__ H,
                                                          const float* __restrict__ X,
                                                          const int* __restrict__ tgt,
                                                          double* __restrict__ ws) {
    __shared__ unsigned short As[TILE * BITS];
    __shared__ unsigned short Bs[TILE * BITS];
    __shared__ int tI[TILE];
    __shared__ int tJ[TILE];
    __shared__ float red[20];

    const int tid = threadIdx.x;
    const int p = blockIdx.x;
    int ti, tj; tile_map(p, ti, tj);
    const int i0 = ti * TILE, j0 = tj * TILE;
    const bool diag = (ti == tj);
    const int lane = tid & 63, wave = tid >> 6;

    if (tid < TILE) { tI[tid] = tgt[i0 + tid]; tJ[tid] = tgt[j0 + tid]; }

    // ---- cls loads hoisted ----
    const int crow = p * 4 + wave;
    float cx1 = -INFINITY, cx2 = -INFINITY, cxt = 0.f;
    if (crow < NPTS) {
        const float* x = X + (size_t)crow * NCLS;
        cx1 = x[lane];
        cx2 = (lane + 64 < NCLS) ? x[lane + 64] : -INFINITY;
        cxt = x[tgt[crow]];
    }

    // ---- staging: 2 batches of 4 float4-pairs (32 VGPRs in flight) ----
#pragma unroll
    for (int bb = 0; bb < 2; ++bb) {
        float4 buf0[4], buf1[4];
#pragma unroll
        for (int it = 0; it < 4; ++it) {
            const int idx  = tid + (bb * 4 + it) * 256;
            const int half = idx >> 10;
            const int lid  = idx & 1023;
            const int row  = lid >> 3;
            const int c    = lid & 7;
            const float* src = H + (size_t)((half ? j0 : i0) + row) * BITS + c * 8;
            buf0[it] = *(const float4*)src;
            buf1[it] = *(const float4*)(src + 4);
        }
#pragma unroll
        for (int it = 0; it < 4; ++it) {
            const int idx  = tid + (bb * 4 + it) * 256;
            const int half = idx >> 10;
            const int lid  = idx & 1023;
            const int row  = lid >> 3;
            const int c    = lid & 7;
            uint4 v;
            v.x = cvt_pk_bf16(buf0[it].x * SCALE, buf0[it].y * SCALE);
            v.y = cvt_pk_bf16(buf0[it].z * SCALE, buf0[it].w * SCALE);
            v.z = cvt_pk_bf16(buf1[it].x * SCALE, buf1[it].y * SCALE);
            v.w = cvt_pk_bf16(buf1[it].z * SCALE, buf1[it].w * SCALE);
            unsigned short* dst = half ? Bs : As;
            *(uint4*)&dst[row * BITS + ((c ^ (row & 7)) * 8)] = v;
        }
    }
    __syncthreads();

    const int wr = wave >> 1, wc = wave & 1;
    const int lrow = lane & 31, hi = lane >> 5;

    f32x16 c00, c01, c10, c11;
#pragma unroll
    for (int e = 0; e < 16; ++e) { c00[e] = 0.f; c01[e] = 0.f; c10[e] = 0.f; c11[e] = 0.f; }

    auto ldfrag = [](const unsigned short* S, int row, int chunk) -> bf16x8 {
        ushort8v r = *(const ushort8v*)&S[row * BITS + ((chunk ^ (row & 7)) * 8)];
        return __builtin_bit_cast(bf16x8, r);
    };

#pragma unroll
    for (int ks = 0; ks < 4; ++ks) {
        const int ch = ks * 2 + hi;
        bf16x8 a0 = ldfrag(As, wr * 64 +      lrow, ch);
        bf16x8 a1 = ldfrag(As, wr * 64 + 32 + lrow, ch);
        bf16x8 b0 = ldfrag(Bs, wc * 64 +      lrow, ch);
        bf16x8 b1 = ldfrag(Bs, wc * 64 + 32 + lrow, ch);
        c00 = __builtin_amdgcn_mfma_f32_32x32x16_bf16(a0, b0, c00, 0, 0, 0);
        c01 = __builtin_amdgcn_mfma_f32_32x32x16_bf16(a0, b1, c01, 0, 0, 0);
        c10 = __builtin_amdgcn_mfma_f32_32x32x16_bf16(a1, b0, c10, 0, 0, 0);
        c11 = __builtin_amdgcn_mfma_f32_32x32x16_bf16(a1, b1, c11, 0, 0, 0);
    }

    // packed epilogue state; split product chains (half-depth dependencies)
    f32x2 prodA0 = {1.f, 1.f}, prodA1 = {1.f, 1.f};
    f32x2 prodS0 = {1.f, 1.f}, prodS1 = {1.f, 1.f};
    f32x2 sT = {0.f, 0.f}, sN = {0.f, 0.f}, sTS = {0.f, 0.f}, sNS = {0.f, 0.f};
    f32x2 sC = {0.f, 0.f};

    if (!diag) {
#pragma unroll
        for (int it = 0; it < 2; ++it) {
            const int rbase = wr * 64 + it * 32 + 4 * hi;
            int4 tr4[4];                        // rows rbase + {0..3, 8..11, 16..19, 24..27}
#pragma unroll
            for (int g = 0; g < 4; ++g)
                tr4[g] = *(const int4*)&tI[rbase + 8 * g];
#pragma unroll
            for (int jt = 0; jt < 2; ++jt) {
                const int tc = tJ[wc * 64 + jt * 32 + lrow];
                const f32x16& C = it ? (jt ? c11 : c10) : (jt ? c01 : c00);
#pragma unroll
                for (int r = 0; r < 16; r += 2) {
                    float t0 = C[r], t1 = C[r + 1];
                    float n0 = __uint_as_float(__float_as_uint(t0) | 0x80000000u);
                    float n1 = __uint_as_float(__float_as_uint(t1) | 0x80000000u);
                    f32x2 t2; t2[0] = t0; t2[1] = t1;
                    f32x2 n2; n2[0] = n0; n2[1] = n1;
                    f32x2 u2;                               // trans pipe
                    u2[0] = fexp2(n0);
                    u2[1] = fexp2(n1);
                    const int* tg = (const int*)&tr4[r >> 2];
                    f32x2 mf;
                    mf[0] = (tg[r & 3]       == tc) ? 1.f : 0.f;
                    mf[1] = (tg[(r & 3) + 1] == tc) ? 1.f : 0.f;
                    f32x2 mu = mf * u2;
                    if ((r >> 1) & 1) { prodA1 = prodA1 + prodA1 * u2; prodS1 = prodS1 + prodS1 * mu; }
                    else              { prodA0 = prodA0 + prodA0 * u2; prodS0 = prodS0 + prodS0 * mu; }
                    sT  = sT  + t2;
                    sN  = sN  + n2;
                    sTS = sTS + mf * t2;
                    sNS = sNS + mf * n2;
                    sC  = sC  + mf;
                }
            }
        }
    } else {
#pragma unroll
        for (int it = 0; it < 2; ++it) {
            const int rbase = wr * 64 + it * 32 + 4 * hi;
            int4 tr4[4];
#pragma unroll
            for (int g = 0; g < 4; ++g)
                tr4[g] = *(const int4*)&tI[rbase + 8 * g];
#pragma unroll
            for (int jt = 0; jt < 2; ++jt) {
                const int lc = wc * 64 + jt * 32 + lrow;
                const int tc = tJ[lc];
                const f32x16& C = it ? (jt ? c11 : c10) : (jt ? c01 : c00);
#pragma unroll
                for (int r = 0; r < 16; r += 2) {
                    float t0 = C[r], t1 = C[r + 1];
                    float n0 = __uint_as_float(__float_as_uint(t0) | 0x80000000u);
                    float n1 = __uint_as_float(__float_as_uint(t1) | 0x80000000u);
                    f32x2 t2; t2[0] = t0; t2[1] = t1;
                    f32x2 n2; n2[0] = n0; n2[1] = n1;
                    f32x2 u2;
                    u2[0] = fexp2(n0);
                    u2[1] = fexp2(n1);
                    const int lr0 = rbase + (r & 3) + 8 * (r >> 2);
                    bool v0 = lc > lr0, v1 = lc > (lr0 + 1);
                    const int* tg = (const int*)&tr4[r >> 2];
                    f32x2 vf; vf[0] = v0 ? 1.f : 0.f; vf[1] = v1 ? 1.f : 0.f;
                    f32x2 mf;
                    mf[0] = (v0 && tg[r & 3]       == tc) ? 1.f : 0.f;
                    mf[1] = (v1 && tg[(r & 3) + 1] == tc) ? 1.f : 0.f;
                    f32x2 vu = vf * u2;
                    f32x2 mu = mf * u2;
                    if ((r >> 1) & 1) { prodA1 = prodA1 + prodA1 * vu; prodS1 = prodS1 + prodS1 * mu; }
                    else              { prodA0 = prodA0 + prodA0 * vu; prodS0 = prodS0 + prodS0 * mu; }
                    sT  = sT  + vf * t2;
                    sN  = sN  + vf * n2;
                    sTS = sTS + mf * t2;
                    sNS = sNS + mf * n2;
                    sC  = sC  + mf;
                }
            }
        }
    }

    // relu-sum = (sum t - sum(-|t|)) / 2 ; merge split product chains
    float pa = (prodA0[0] * prodA0[1]) * (prodA1[0] * prodA1[1]);
    float ps = (prodS0[0] * prodS0[1]) * (prodS1[0] * prodS1[1]);
    float s_all  = 0.5f * ((sT[0] + sT[1]) - (sN[0] + sN[1])) + flog2(pa);
    float s_same = 0.5f * ((sTS[0] + sTS[1]) - (sNS[0] + sNS[1])) + flog2(ps);
    float t_same = sTS[0] + sTS[1];
    float c_same = sC[0] + sC[1];

#pragma unroll
    for (int d = 32; d > 0; d >>= 1) {
        s_all  += __shfl_xor(s_all,  d, 64);
        s_same += __shfl_xor(s_same, d, 64);
        t_same += __shfl_xor(t_same, d, 64);
        c_same += __shfl_xor(c_same, d, 64);
    }
    if (lane == 0) {
        red[wave] = s_all; red[4 + wave] = s_same;
        red[8 + wave] = t_same; red[12 + wave] = c_same;
    }

    {   // cls softmax on preloaded registers
        float nll = 0.f;
        if (crow < NPTS) {
            float m = fmaxf(cx1, cx2);
#pragma unroll
            for (int d = 32; d > 0; d >>= 1) m = fmaxf(m, __shfl_xor(m, d, 64));
            float e = __expf(cx1 - m) + ((lane + 64 < NCLS) ? __expf(cx2 - m) : 0.f);
#pragma unroll
            for (int d = 32; d > 0; d >>= 1) e += __shfl_xor(e, d, 64);
            if (lane == 0) nll = m + __logf(e) - cxt;
        }
        if (lane == 0) red[16 + wave] = nll;
    }
    __syncthreads();
    if (tid == 0) {
        ws[p]              = (double)red[0]  + (double)red[1]  + (double)red[2]  + (double)red[3];
        ws[NPAIRS + p]     = (double)red[4]  + (double)red[5]  + (double)red[6]  + (double)red[7];
        ws[2 * NPAIRS + p] = (double)red[8]  + (double)red[9]  + (double)red[10] + (double)red[11];
        ws[3 * NPAIRS + p] = (double)red[12] + (double)red[13] + (double)red[14] + (double)red[15];
        ws[4 * NPAIRS + p] = (double)red[16] + (double)red[17] + (double)red[18] + (double)red[19];
    }
}

// ---------------------------------------------------------------------------
// Finalize (1024 threads, no histogram): S1 = 2 * cnt_same; ln2 fold.
// ---------------------------------------------------------------------------
__global__ __launch_bounds__(1024) void final_kernel(const double* __restrict__ ws,
                                                     float* __restrict__ out) {
    __shared__ double r0[1024], r1[1024], r2[1024], r3[1024], rc[1024];
    const int tid = threadIdx.x;

    double a = 0.0, s = 0.0, t = 0.0, n = 0.0, c = 0.0;
    for (int i = tid; i < NPAIRS; i += 1024) {
        a += ws[i];
        s += ws[NPAIRS + i];
        t += ws[2 * NPAIRS + i];
        n += ws[3 * NPAIRS + i];
        c += ws[4 * NPAIRS + i];
    }
    r0[tid] = a; r1[tid] = s; r2[tid] = t; r3[tid] = n; rc[tid] = c;
    __syncthreads();
    for (int sd = 512; sd > 0; sd >>= 1) {
        if (tid < sd) {
            r0[tid] += r0[tid + sd];
            r1[tid] += r1[tid + sd];
            r2[tid] += r2[tid + sd];
            r3[tid] += r3[tid + sd];
            rc[tid] += rc[tid + sd];
        }
        __syncthreads();
    }

    if (tid == 0) {
        const double Nd = (double)NPTS;
        double S1 = 2.0 * r3[0];                 // n_pos - N (exact)
        double S0 = Nd * Nd - (S1 + Nd);
        if (S0 == 0.0) S0 = 1.0;
        if (S1 == 0.0) S1 = 1.0;
        const double S = S0 + S1;
        const double sum_lower =
            ((S / S0) * (r0[0] - r1[0]) + (S / S1) * (r1[0] - r2[0])) * LN2;
        const double count = Nd * (Nd - 1.0) * 0.5;
        const double hash_loss = sum_lower / count;
        const double cls_loss  = rc[0] / Nd;
        const double loss = 1.0 * cls_loss + 0.01 * hash_loss;
        out[0] = (float)hash_loss;
        out[1] = (float)cls_loss;
        out[2] = (float)loss;
    }
}

// ---------------------------------------------------------------------------
extern "C" void kernel_launch(void* const* d_in, const int* in_sizes, int n_in,
                              void* d_out, int out_size, void* d_ws, size_t ws_size,
                              hipStream_t stream) {
    const float* H   = (const float*)d_in[0];
    const float* X   = (const float*)d_in[1];
    const int*   tgt = (const int*)d_in[2];
    float* out = (float*)d_out;
    double* wsd = (double*)d_ws;

    hash_cls_kernel<<<NPAIRS, 256, 0, stream>>>(H, X, tgt, wsd);
    final_kernel<<<1, 1024, 0, stream>>>(wsd, out);
}